// Round 8
// baseline (498.777 us; speedup 1.0000x reference)
//
#include <hip/hip_runtime.h>

#define NN 20000
#define NP 20032   // padded rows
#define EE 320000
#define TT 12
#define HH 128
#define FF 16
#define CC 16
#define HOR 6

// binning-sort parameters (CSR build)
#define NB 313      // buckets of 64 dst nodes
#define WPT 84      // binning workgroups per timestep
#define CHE 3812    // edges per binning WG (ceil(EE/WPT) rounded to mult of 4)

#define AGG_GRID 1896   // 8 XCDs x 3 half-timesteps x 79 blocks
#define HGA_GRID 15024  // 12*NP*16/256

typedef __attribute__((ext_vector_type(8))) short short8;
typedef __attribute__((ext_vector_type(4))) float f32x4;

__device__ __forceinline__ float blo(unsigned int u) {
    union { float f; unsigned int i; } v; v.i = u << 16; return v.f;
}
__device__ __forceinline__ float bhi(unsigned int u) {
    union { float f; unsigned int i; } v; v.i = u & 0xffff0000u; return v.f;
}
__device__ __forceinline__ unsigned short f2b(float f) {
    union { float f; unsigned int i; } v; v.f = f;
    unsigned int x = v.i;
    return (unsigned short)((x + 0x7fffu + ((x >> 16) & 1u)) >> 16);
}
__device__ __forceinline__ unsigned int pck(float lo, float hi) {
    return ((unsigned int)f2b(hi) << 16) | f2b(lo);
}
__device__ __forceinline__ void addrow(float* acc, uint4 r) {
    acc[0] += blo(r.x); acc[1] += bhi(r.x);
    acc[2] += blo(r.y); acc[3] += bhi(r.y);
    acc[4] += blo(r.z); acc[5] += bhi(r.z);
    acc[6] += blo(r.w); acc[7] += bhi(r.w);
}

// ---------------- setup kernels ----------------
__global__ void k_zero(int* p, int n) {
    int i = blockIdx.x * 256 + threadIdx.x;
    if (i < n) p[i] = 0;
}

// ---- CSR build phase A: LDS counting-sort of each WG's chunk, coalesced write-out ----
__global__ __launch_bounds__(512) void k_binA(const int* __restrict__ ei,
                                              int* __restrict__ gData,
                                              int* __restrict__ pcnt,
                                              int* __restrict__ pofs) {
    int wg = blockIdx.x;
    int t = wg / WPT, w = wg - t * WPT;
    __shared__ int lcnt[NB];
    __shared__ int sm[512];
    __shared__ __align__(16) int elist[CHE];
    int tid = threadIdx.x;
    for (int i = tid; i < NB; i += 512) lcnt[i] = 0;
    __syncthreads();
    int e0 = w * CHE, e1 = min(EE, e0 + CHE);
    int total = e1 - e0;                       // always a multiple of 4
    const int* si = ei + (size_t)t * 2 * EE;
    const int* di = si + EE;
    int eA = e0 + tid * 4, eB = eA + 2048;
    bool hA = eA < e1, hB = eB < e1;
    int sA[4], dA[4], pA[4], sB[4], dB[4], pB[4];
    if (hA) {
        int4 s4 = *(const int4*)(si + eA);
        int4 d4 = *(const int4*)(di + eA);
        sA[0] = s4.x; sA[1] = s4.y; sA[2] = s4.z; sA[3] = s4.w;
        dA[0] = d4.x; dA[1] = d4.y; dA[2] = d4.z; dA[3] = d4.w;
    }
    if (hB) {
        int4 s4 = *(const int4*)(si + eB);
        int4 d4 = *(const int4*)(di + eB);
        sB[0] = s4.x; sB[1] = s4.y; sB[2] = s4.z; sB[3] = s4.w;
        dB[0] = d4.x; dB[1] = d4.y; dB[2] = d4.z; dB[3] = d4.w;
    }
    if (hA) {
#pragma unroll
        for (int k = 0; k < 4; k++) pA[k] = atomicAdd(&lcnt[dA[k] >> 6], 1);
    }
    if (hB) {
#pragma unroll
        for (int k = 0; k < 4; k++) pB[k] = atomicAdd(&lcnt[dB[k] >> 6], 1);
    }
    __syncthreads();
    sm[tid] = (tid < NB) ? lcnt[tid] : 0;
    __syncthreads();
    for (int off = 1; off < 512; off <<= 1) {
        int u = (tid >= off) ? sm[tid - off] : 0;
        __syncthreads();
        sm[tid] += u;
        __syncthreads();
    }
    if (tid < NB) {
        int v = lcnt[tid];
        int ex = sm[tid] - v;
        size_t o = (size_t)(t * WPT + w) * NB + tid;
        pcnt[o] = v;
        pofs[o] = ex;
        sm[tid] = ex;      // sm now holds exclusive bucket offsets
    }
    __syncthreads();
    if (hA) {
#pragma unroll
        for (int k = 0; k < 4; k++) {
            int b = dA[k] >> 6;
            elist[sm[b] + pA[k]] = ((dA[k] & 63) << 16) | sA[k];
        }
    }
    if (hB) {
#pragma unroll
        for (int k = 0; k < 4; k++) {
            int b = dB[k] >> 6;
            elist[sm[b] + pB[k]] = ((dB[k] & 63) << 16) | sB[k];
        }
    }
    __syncthreads();
    int* gOut = gData + (size_t)(t * WPT + w) * CHE;
    for (int i = tid * 4; i < total; i += 2048)
        *(int4*)(gOut + i) = *(const int4*)&elist[i];
}

// ---- fused bucket-sum + exclusive scan per timestep ----
__global__ __launch_bounds__(512) void k_bscan2(const int* __restrict__ pcnt,
                                                int* __restrict__ bbase,
                                                int* __restrict__ rowptr) {
    int t = blockIdx.x, tid = threadIdx.x;
    __shared__ int sm[512];
    int v = 0;
    if (tid < NB)
        for (int w = 0; w < WPT; w++) v += pcnt[(size_t)(t * WPT + w) * NB + tid];
    sm[tid] = v;
    __syncthreads();
    for (int off = 1; off < 512; off <<= 1) {
        int u = (tid >= off) ? sm[tid - off] : 0;
        __syncthreads();
        sm[tid] += u;
        __syncthreads();
    }
    if (tid < NB) bbase[t * NB + tid] = sm[tid] - v;
    if (tid == 511) rowptr[(size_t)t * (NN + 1) + NN] = sm[511];
}

__global__ __launch_bounds__(256) void k_placeB(const int* __restrict__ gData,
                                                const int* __restrict__ pcnt,
                                                const int* __restrict__ pofs,
                                                const int* __restrict__ bbase,
                                                int* __restrict__ rowptr,
                                                float* __restrict__ dinv,
                                                unsigned short* __restrict__ csr) {
    int t = blockIdx.x / NB, b = blockIdx.x - t * NB;
    int tid = threadIdx.x;
    __shared__ int scnt[WPT], sofs[WPT], cofs[WPT + 1];
    __shared__ int elist[2048];
    __shared__ int cnt64[64], lofs[64], place[64];
    if (tid < WPT) {
        size_t o = (size_t)(t * WPT + tid) * NB + b;
        scnt[tid] = pcnt[o];
        sofs[tid] = pofs[o];
    }
    if (tid < 64) cnt64[tid] = 0;
    __syncthreads();
    if (tid == 0) {
        int s = 0;
        for (int w = 0; w < WPT; w++) { cofs[w] = s; s += scnt[w]; }
        cofs[WPT] = s;
    }
    __syncthreads();
    int total = cofs[WPT];
    int wv = tid >> 6, lane = tid & 63;
    for (int w = wv; w < WPT; w += 4) {
        int c = scnt[w], o = cofs[w];
        const int* sp = gData + (size_t)(t * WPT + w) * CHE + sofs[w];
        for (int i = lane; i < c; i += 64) elist[o + i] = sp[i];
    }
    __syncthreads();
    for (int i = tid; i < total; i += 256) atomicAdd(&cnt64[elist[i] >> 16], 1);
    __syncthreads();
    if (tid == 0) {
        int s = 0;
        for (int j = 0; j < 64; j++) { lofs[j] = s; place[j] = s; s += cnt64[j]; }
    }
    __syncthreads();
    int base = bbase[t * NB + b];
    int n = b * 64 + tid;
    if (tid < 64 && n < NN) {
        rowptr[(size_t)t * (NN + 1) + n] = base + lofs[tid];
        dinv[(size_t)t * NN + n] = rsqrtf(1.0f + (float)cnt64[tid]);
    }
    unsigned short* cbase = csr + (size_t)t * EE + base;
    for (int i = tid; i < total; i += 256) {
        int en = elist[i];
        int r = atomicAdd(&place[en >> 16], 1);
        cbase[r] = (unsigned short)(en & 0xffff);
    }
}

// ---------------- fallback CSR build (small ws_size) ----------------
__global__ void k_count(const int* __restrict__ ei, int* __restrict__ cnt) {
    int idx = blockIdx.x * 256 + threadIdx.x;
    if (idx >= TT * EE) return;
    int t = idx / EE, e = idx - t * EE;
    int d = ei[t * 2 * EE + EE + e];
    atomicAdd(&cnt[t * NN + d], 1);
}

__global__ void k_dinvF(const int* __restrict__ cnt, float* __restrict__ dinv) {
    int idx = blockIdx.x * 256 + threadIdx.x;
    if (idx >= TT * NN) return;
    dinv[idx] = 1.0f / sqrtf(1.0f + (float)cnt[idx]);
}

__global__ void k_scan(const int* __restrict__ cnt, int* __restrict__ rowptr, int* __restrict__ wofs) {
    int t = blockIdx.x;
    const int* c = cnt + t * NN;
    int* rp = rowptr + t * (NN + 1);
    int* wo = wofs + t * NN;
    __shared__ int sums[1024];
    int tid = threadIdx.x;
    const int CH2 = 20;
    int base = tid * CH2;
    int loc[CH2];
    int s = 0;
    for (int i = 0; i < CH2; i++) { int ix = base + i; int v = (ix < NN) ? c[ix] : 0; loc[i] = s; s += v; }
    sums[tid] = s;
    __syncthreads();
    for (int off = 1; off < 1024; off <<= 1) {
        int v = (tid >= off) ? sums[tid - off] : 0;
        __syncthreads();
        sums[tid] += v;
        __syncthreads();
    }
    int excl = (tid > 0) ? sums[tid - 1] : 0;
    for (int i = 0; i < CH2; i++) {
        int ix = base + i;
        if (ix < NN) { int e = excl + loc[i]; rp[ix] = e; wo[ix] = e; }
    }
    if (tid == 1023) rp[NN] = sums[1023];
}

__global__ void k_place(const int* __restrict__ ei, int* __restrict__ wofs,
                        unsigned short* __restrict__ csr) {
    int idx = blockIdx.x * 256 + threadIdx.x;
    if (idx >= TT * EE) return;
    int t = idx / EE, e = idx - t * EE;
    int s = ei[t * 2 * EE + e];
    int d = ei[t * 2 * EE + EE + e];
    int pos = atomicAdd(&wofs[t * NN + d], 1);
    csr[t * EE + pos] = (unsigned short)s;
}

// ---------------- fused TCN+proj weight prep (+ bias block) ----------------
// Bf32[384][128]: rows 0-127 = M2 (coeff of h_{t-2}), 128-255 = M1 (h_{t-1}),
// 256-383 = Mh (hg_t). Bpk = MFMA-packed single-step B for the decoder.
__global__ void k_wprepB(const float* __restrict__ cw, const float* __restrict__ pw,
                         const float* __restrict__ cb, const float* __restrict__ pb,
                         unsigned short* __restrict__ Bpk, float* __restrict__ Bf32,
                         float* __restrict__ bias) {
    int idx = blockIdx.x * 256 + threadIdx.x;
    if (blockIdx.x == 192) {
        int h = threadIdx.x;
        if (h < HH) {
            float m = pb[h];
            for (int d = 0; d < 3; d++)
                for (int o = 0; o < HH; o++)
                    m += cb[d * HH + o] * pw[h * 384 + d * HH + o];
            bias[h] = m;
        }
        return;
    }
    if (idx >= 384 * HH) return;
    int kk = idx / HH, h = idx - kk * HH;
    float m = 0.f;
    if (kk < 128) {
        int i = kk;
        for (int o = 0; o < HH; o++)
            m += cw[((1 * HH + o) * HH + i) * 3 + 0] * pw[h * 384 + 128 + o];
    } else if (kk < 256) {
        int i = kk - 128;
        for (int o = 0; o < HH; o++)
            m += cw[((0 * HH + o) * HH + i) * 3 + 0] * pw[h * 384 + o];
    } else {
        int i = kk - 256;
        for (int d = 0; d < 3; d++)
            for (int o = 0; o < HH; o++)
                m += cw[((d * HH + o) * HH + i) * 3 + 1] * pw[h * 384 + d * HH + o];
    }
    Bf32[kk * HH + h] = m;
    int ki = kk >> 5, r = kk & 31, q = r >> 3, j = r & 7, nt = h >> 4, ln = q * 16 + (h & 15);
    Bpk[(size_t)((ki * 8 + nt) * 64 + ln) * 8 + j] = f2b(m);
}

// ---------------- encoder collapse: T-chain weight build ----------------
// h_t = h_{t-2}M2 + h_{t-1}M1 + hg_t Mh + b  (linear in hg_s). Decoder needs
// only h_10, h_11:  h_10 = sum_s hg_s T_{10-s} + P_10 ; h_11 analogous.
// T_0 = Mh, T_j = T_{j-1}M1 + T_{j-2}M2 ; P_0 = b, P_j = P_{j-1}M1 + P_{j-2}M2 + b.
// Block r (0..127) computes row r of every T_j and writes it straight into the
// MFMA-packed Bq (K=48 kb-blocks = 12 slices x 4, N=256 = [h10|h11]) using
// EXACTLY k_packP's (kk,c)->(kb,nt,ln,j) mapping. Block 128 does the bias chain.
__global__ __launch_bounds__(128) void k_tchain(const float* __restrict__ Bf32,
                                                const float* __restrict__ biasT,
                                                unsigned short* __restrict__ Bq,
                                                float* __restrict__ biasQ) {
    __shared__ float v1[128], v2[128];
    int c = threadIdx.x;
    int r = blockIdx.x;
    const float* M2 = Bf32;
    const float* M1 = Bf32 + 128 * HH;
    const float* Mh = Bf32 + 256 * HH;
    if (r < 128) {
        int q4 = (r & 31) >> 3, jj = r & 7, rb = r >> 5;
        v1[c] = Mh[r * HH + c];     // T_0 row r
        v2[c] = 0.f;                // T_{-1}
        __syncthreads();
        // write T_0: half0 at s=10, half1 at s=11
        {
            float val = v1[c];
            int kb0 = 10 * 4 + rb, nt0 = c >> 4, ln = q4 * 16 + (c & 15);
            Bq[((size_t)(kb0 * 16 + nt0) * 64 + ln) * 8 + jj] = f2b(val);
            int kb1 = 11 * 4 + rb, nt1 = 8 + (c >> 4);
            Bq[((size_t)(kb1 * 16 + nt1) * 64 + ln) * 8 + jj] = f2b(val);
        }
        for (int j = 1; j < 12; j++) {
            float acc = 0.f;
            for (int k = 0; k < 128; k++)
                acc += v1[k] * M1[k * HH + c] + v2[k] * M2[k * HH + c];
            __syncthreads();
            v2[c] = v1[c]; v1[c] = acc;
            __syncthreads();
            int ln = q4 * 16 + (c & 15);
            if (j <= 10) {      // half0 (h_10): s = 10-j
                int kb = (10 - j) * 4 + rb, nt = c >> 4;
                Bq[((size_t)(kb * 16 + nt) * 64 + ln) * 8 + jj] = f2b(acc);
            }
            {                   // half1 (h_11): s = 11-j
                int kb = (11 - j) * 4 + rb, nt = 8 + (c >> 4);
                Bq[((size_t)(kb * 16 + nt) * 64 + ln) * 8 + jj] = f2b(acc);
            }
        }
        // zero-fill half0 of slice s=11 (h_10 has no hg_11 term)
        {
            int kb = 11 * 4 + rb, nt = c >> 4, ln = q4 * 16 + (c & 15);
            Bq[((size_t)(kb * 16 + nt) * 64 + ln) * 8 + jj] = 0;
        }
    } else {
        // bias chain: after loop v2 = P_10, v1 = P_11
        v1[c] = biasT[c];
        v2[c] = 0.f;
        __syncthreads();
        for (int j = 1; j < 12; j++) {
            float acc = biasT[c];
            for (int k = 0; k < 128; k++)
                acc += v1[k] * M1[k * HH + c] + v2[k] * M2[k * HH + c];
            __syncthreads();
            v2[c] = v1[c]; v1[c] = acc;
            __syncthreads();
        }
        biasQ[c] = v2[c];
        biasQ[128 + c] = v1[c];
    }
}

// ---------------- encoder front-end ----------------
__global__ void k_xs(const float* __restrict__ x, const float* __restrict__ dinv,
                     unsigned short* __restrict__ xs) {
    int idx = blockIdx.x * 256 + threadIdx.x;
    if (idx >= TT * NN) return;
    float dn = dinv[idx];
    const float4* xr = (const float4*)(x + (size_t)idx * FF);
    unsigned int res[8];
#pragma unroll
    for (int k = 0; k < 4; k++) {
        float4 v = xr[k];
        res[2 * k]     = pck(v.x * dn, v.y * dn);
        res[2 * k + 1] = pck(v.z * dn, v.w * dn);
    }
    uint4* dst = (uint4*)(xs + (size_t)idx * FF);
    dst[0] = *(uint4*)(res);
    dst[1] = *(uint4*)(res + 4);
}

// XCD-affinity aggregation (kept from R7: -20us vs round-robin).
__global__ __launch_bounds__(256) void k_aggX(const unsigned short* __restrict__ xsA,
                                              const unsigned short* __restrict__ csrA,
                                              const int* __restrict__ rpA,
                                              const float* __restrict__ dinvA,
                                              float* __restrict__ zA) {
    int bid = blockIdx.x;
    int x = bid & 7, k = bid >> 3;           // target XCD, slot 0..236
    int h = 3 * x + k / 79;                  // half-timestep 0..23
    int g = h >> 1;                          // timestep
    int nb = (h & 1) * 79 + (k % 79);        // 128-row block within timestep
    int tid = threadIdx.x;
    int r = tid >> 1, eo = tid & 1;          // 2 threads per row
    int n = nb * 128 + r;
    if (n >= NN) return;
    const unsigned short* xs = xsA + (size_t)g * NN * FF;
    const unsigned short* csr = csrA + (size_t)g * EE;
    const int* rp = rpA + (size_t)g * (NN + 1);
    float acc[16];
#pragma unroll
    for (int i = 0; i < 16; i++) acc[i] = 0.f;
    int j0 = rp[n], j1 = rp[n + 1];
    int j = j0 + eo;
    for (; j + 2 < j1; j += 4) {
        int s0 = csr[j], s1 = csr[j + 2];
        const uint4* p0 = (const uint4*)(xs + (size_t)s0 * FF);
        const uint4* p1 = (const uint4*)(xs + (size_t)s1 * FF);
        uint4 a0 = p0[0], a1 = p0[1], b0 = p1[0], b1 = p1[1];
        addrow(acc, a0); addrow(acc + 8, a1);
        addrow(acc, b0); addrow(acc + 8, b1);
    }
    if (j < j1) {
        const uint4* p0 = (const uint4*)(xs + (size_t)csr[j] * FF);
        uint4 a0 = p0[0], a1 = p0[1];
        addrow(acc, a0); addrow(acc + 8, a1);
    }
#pragma unroll
    for (int i = 0; i < 16; i++) acc[i] += __shfl_xor(acc[i], 1);
    if (eo == 0) {
        const uint4* sp = (const uint4*)(xs + (size_t)n * FF);
        uint4 a = sp[0], b4 = sp[1];
        addrow(acc, a); addrow(acc + 8, b4);
        float dn = dinvA[(size_t)g * NN + n];
        float4* zo = (float4*)(zA + (size_t)g * NP * FF + (size_t)n * FF);
#pragma unroll
        for (int k2 = 0; k2 < 4; k2++)
            zo[k2] = make_float4(acc[4 * k2] * dn, acc[4 * k2 + 1] * dn,
                                 acc[4 * k2 + 2] * dn, acc[4 * k2 + 3] * dn);
    }
}

// ---------------- all-timestep hg: hgAll[s][n][128] = relu(z[s][n]*Wg + gb) ----------------
// One thread per (row, 8-col group): z row broadcast via L1, 16B coalesced stores.
__global__ __launch_bounds__(256) void k_hgA(const float* __restrict__ z12,
                                             const float* __restrict__ gw,
                                             const float* __restrict__ gb,
                                             unsigned short* __restrict__ hgAll) {
    int g = blockIdx.x * 256 + threadIdx.x;     // [0, 12*NP*16)
    int row = g >> 4, cg = g & 15;
    int c0 = cg * 8;
    const float4* zp = (const float4*)(z12 + (size_t)row * FF);
    float4 z0 = zp[0], z1 = zp[1], z2 = zp[2], z3 = zp[3];
    float zr[16] = {z0.x, z0.y, z0.z, z0.w, z1.x, z1.y, z1.z, z1.w,
                    z2.x, z2.y, z2.z, z2.w, z3.x, z3.y, z3.z, z3.w};
    float s[8];
#pragma unroll
    for (int c = 0; c < 8; c++) s[c] = gb[c0 + c];
#pragma unroll
    for (int f = 0; f < 16; f++) {
        const float4* wp = (const float4*)(gw + f * HH + c0);
        float4 w0 = wp[0], w1 = wp[1];
        float zf = zr[f];
        s[0] += zf * w0.x; s[1] += zf * w0.y; s[2] += zf * w0.z; s[3] += zf * w0.w;
        s[4] += zf * w1.x; s[5] += zf * w1.y; s[6] += zf * w1.z; s[7] += zf * w1.w;
    }
    unsigned int res[4];
#pragma unroll
    for (int k = 0; k < 4; k++)
        res[k] = pck(fmaxf(s[2 * k], 0.f), fmaxf(s[2 * k + 1], 0.f));
    *(uint4*)(hgAll + (size_t)row * HH + c0) = *(uint4*)res;
}

// ---------------- ONE big encoder gemm: [h10|h11] = sum_s hg_s * T + P ----------------
// 626 blocks x 512 thr (8 waves: 2 row-groups x 4 col-groups). K = 48 kb-blocks.
// Barrier-free unrolled K-loop, plain cached loads (Bq 768KB L2-hot, hgAll L3).
__global__ __launch_bounds__(512, 4) void k_gemmE(const unsigned short* __restrict__ hgAll,
                                                  const unsigned short* __restrict__ Bq,
                                                  const float* __restrict__ biasQ,
                                                  unsigned short* __restrict__ out0,
                                                  unsigned short* __restrict__ out1) {
    __shared__ float bqs[256];
    __shared__ __align__(16) unsigned short csh[32 * 264];
    int tid = threadIdx.x;
    int wid = tid >> 6, lane = tid & 63;
    int rg = wid & 1, cg = wid >> 1;
    int m0b = blockIdx.x * 32;
    int m0 = m0b + rg * 16;
    int mr = lane & 15, q = lane >> 4;
    if (tid < 256) bqs[tid] = biasQ[tid];
    int nt0 = cg * 4;
    f32x4 acc[4];
#pragma unroll
    for (int j = 0; j < 4; j++) acc[j] = (f32x4){0.f, 0.f, 0.f, 0.f};
#pragma unroll
    for (int kb = 0; kb < 48; kb++) {
        short8 bf[4];
#pragma unroll
        for (int j = 0; j < 4; j++)
            bf[j] = *(const short8*)(Bq + ((size_t)(kb * 16 + nt0 + j) * 64 + lane) * 8);
        int s = kb >> 2;
        short8 af = *(const short8*)(hgAll + ((size_t)(s * NP) + m0 + mr) * HH +
                                     (kb & 3) * 32 + q * 8);
#pragma unroll
        for (int j = 0; j < 4; j++)
            acc[j] = __builtin_amdgcn_mfma_f32_16x16x32_bf16(af, bf[j], acc[j], 0, 0, 0);
    }
    __syncthreads();
#pragma unroll
    for (int j = 0; j < 4; j++) {
        int c = (nt0 + j) * 16 + mr;
        float bv = bqs[c];
#pragma unroll
        for (int r = 0; r < 4; r++)
            csh[(rg * 16 + q * 4 + r) * 264 + c] = f2b(acc[j][r] + bv);
    }
    __syncthreads();
#pragma unroll
    for (int i = 0; i < 2; i++) {
        int idx = i * 512 + tid;        // 0..1023: 32 rows x 32 chunks
        int row = idx >> 5, c8 = (idx & 31) * 8;
        short8 v = *(const short8*)&csh[row * 264 + c8];
        if (c8 < 128) *(short8*)(out0 + (size_t)(m0b + row) * HH + c8) = v;
        else          *(short8*)(out1 + (size_t)(m0b + row) * HH + (c8 - 128)) = v;
    }
}

// hg A-fragment (decoder): lane computes 32 hg values for row mr of a 16-row block
__device__ __forceinline__ void hg_frag(const float* zsh, const float* Wg, const float* gbs,
                                        int mr, int q, short8* hgf) {
    float zr[16];
    {
        const float4* zp = (const float4*)(zsh + mr * FF);
        float4 z0 = zp[0], z1 = zp[1], z2 = zp[2], z3 = zp[3];
        zr[0] = z0.x; zr[1] = z0.y; zr[2] = z0.z; zr[3] = z0.w;
        zr[4] = z1.x; zr[5] = z1.y; zr[6] = z1.z; zr[7] = z1.w;
        zr[8] = z2.x; zr[9] = z2.y; zr[10] = z2.z; zr[11] = z2.w;
        zr[12] = z3.x; zr[13] = z3.y; zr[14] = z3.z; zr[15] = z3.w;
    }
#pragma unroll
    for (int k2 = 0; k2 < 4; k2++) {
        float s[8];
#pragma unroll
        for (int c = 0; c < 8; c++) s[c] = gbs[k2 * 32 + q * 8 + c];
#pragma unroll
        for (int f = 0; f < 16; f++) {
            const float4* wp = (const float4*)(Wg + f * HH + k2 * 32 + q * 8);
            float4 w0 = wp[0], w1 = wp[1];
            float zf = zr[f];
            s[0] += zf * w0.x; s[1] += zf * w0.y; s[2] += zf * w0.z; s[3] += zf * w0.w;
            s[4] += zf * w1.x; s[5] += zf * w1.y; s[6] += zf * w1.z; s[7] += zf * w1.w;
        }
#pragma unroll
        for (int c = 0; c < 8; c++) hgf[k2][c] = (short)f2b(fmaxf(s[c], 0.f));
    }
}

// ---------------- decoder fused step: [gather] + gemm + head + feedback ----------------
// 16-row blocks, 4 waves x (16 rows x 32 cols). (unchanged from R6/R7)
__global__ __launch_bounds__(256, 3) void k_gemmF2(const unsigned short* __restrict__ a0,
                                                   const unsigned short* __restrict__ a1,
                                                   const float* __restrict__ zt, int gather,
                                                   const float* __restrict__ gw,
                                                   const float* __restrict__ gb,
                                                   const unsigned short* __restrict__ Bpk,
                                                   const float* __restrict__ bias,
                                                   unsigned short* __restrict__ out,
                                                   const float* __restrict__ hw,
                                                   const float* __restrict__ hbv,
                                                   const float* __restrict__ dinvN,
                                                   const int* __restrict__ rp,
                                                   const unsigned short* __restrict__ csr,
                                                   unsigned short* __restrict__ xsD,
                                                   float* __restrict__ yout) {
    __shared__ float Wg[FF * HH];
    __shared__ float Whs[CC * 132];     // padded: kills 16-way head bank conflict
    __shared__ float gbs[HH], biasS[HH], hbS[CC];
    __shared__ float zsh[16 * FF];
    __shared__ __align__(16) unsigned short hgD[16 * 136];
    __shared__ unsigned short hsh[16 * 136];
    __shared__ float ysh[16 * 17];
    int tid = threadIdx.x;
    int wid = tid >> 6, lane = tid & 63;
    int m0b = blockIdx.x * 16;
    int mr = lane & 15, q = lane >> 4;
    for (int i = tid; i < FF * HH; i += 256) {
        Wg[i] = gw[i];
        Whs[(i >> 7) * 132 + (i & 127)] = hw[i];
    }
    if (tid < HH) { gbs[tid] = gb[tid]; biasS[tid] = bias[tid]; }
    if (tid < CC) hbS[tid] = hbv[tid];
    if (!gather) {
        if (tid < 16 * FF) zsh[tid] = zt[(size_t)m0b * FF + tid];
    } else {
        // in-tile 16-dim aggregation from xsD: 16 threads/row (2 halves x 8-way edges)
        int r = tid >> 4, p = tid & 15, half = p & 1, eo = p >> 1;
        int n = m0b + r;
        float a[8];
#pragma unroll
        for (int k = 0; k < 8; k++) a[k] = 0.f;
        if (n < NN) {
            int j0 = rp[n], j1 = rp[n + 1];
            for (int j = j0 + eo; j < j1; j += 8) {
                int s = csr[j];
                uint4 v = *(const uint4*)(xsD + (size_t)s * FF + half * 8);
                addrow(a, v);
            }
        }
#pragma unroll
        for (int k = 0; k < 8; k++) {
            a[k] += __shfl_xor(a[k], 2);
            a[k] += __shfl_xor(a[k], 4);
            a[k] += __shfl_xor(a[k], 8);
        }
        if (n < NN && eo == 0) {
            uint4 sv = *(const uint4*)(xsD + (size_t)n * FF + half * 8);
            addrow(a, sv);
            float dn = dinvN[n];
#pragma unroll
            for (int k = 0; k < 8; k++) zsh[r * FF + half * 8 + k] = a[k] * dn;
        }
    }
    __syncthreads();
    if (wid == 0) {
        short8 hgf[4];
        hg_frag(zsh, Wg, gbs, mr, q, hgf);
#pragma unroll
        for (int k2 = 0; k2 < 4; k2++)
            *(short8*)&hgD[mr * 136 + k2 * 32 + q * 8] = hgf[k2];
    }
    __syncthreads();
    int nt0 = wid * 2;                  // wave's 2 col tiles (32 cols)
    f32x4 acc[2];
#pragma unroll
    for (int j = 0; j < 2; j++) acc[j] = (f32x4){0.f, 0.f, 0.f, 0.f};
#pragma unroll
    for (int ki = 0; ki < 12; ki++) {
        short8 bf[2];
#pragma unroll
        for (int j = 0; j < 2; j++)
            bf[j] = *(const short8*)(Bpk + (size_t)((ki * 8 + nt0 + j) * 64 + lane) * 8);
        short8 af;
        if (ki < 4)
            af = *(const short8*)(a0 + (size_t)(m0b + mr) * HH + ki * 32 + q * 8);
        else if (ki < 8)
            af = *(const short8*)(a1 + (size_t)(m0b + mr) * HH + (ki - 4) * 32 + q * 8);
        else
            af = *(const short8*)&hgD[mr * 136 + (ki - 8) * 32 + q * 8];
#pragma unroll
        for (int j = 0; j < 2; j++)
            acc[j] = __builtin_amdgcn_mfma_f32_16x16x32_bf16(af, bf[j], acc[j], 0, 0, 0);
    }
#pragma unroll
    for (int j = 0; j < 2; j++) {
        int feat = (nt0 + j) * 16 + mr;
        float bv = biasS[feat];
#pragma unroll
        for (int r = 0; r < 4; r++)
            hsh[(q * 4 + r) * 136 + feat] = f2b(acc[j][r] + bv);
    }
    __syncthreads();
    // coalesced h write-out (16B/lane): 16 rows x 16 chunks = 256
    {
        int row = tid >> 4, c8 = (tid & 15) * 8;
        *(short8*)(out + (size_t)(m0b + row) * HH + c8) =
            *(const short8*)&hsh[row * 136 + c8];
    }
    // head: y[n][c] = hb[c] + sum_k h[n][k]*Wh[c][k]; 1 thread per (row, col)
    {
        int r = tid >> 4, c = tid & 15;
        float y = hbS[c];
        for (int k = 0; k < HH; k++)
            y += blo((unsigned int)hsh[r * 136 + k]) * Whs[c * 132 + k];
        ysh[r * 17 + c] = y;
        int gn = m0b + r;
        if (gn < NN) yout[(size_t)gn * CC + c] = y;
    }
    __syncthreads();
    // next-step xs: xsD[n][k] = bf16(y[n][k] * dinv[n])
    if (tid < 16) {
        int gn = m0b + tid;
        if (gn < NN) {
            float dn = dinvN[gn];
            unsigned int res[8];
#pragma unroll
            for (int k = 0; k < 8; k++)
                res[k] = pck(ysh[tid * 17 + 2 * k] * dn, ysh[tid * 17 + 2 * k + 1] * dn);
            uint4* dst = (uint4*)(xsD + (size_t)gn * FF);
            dst[0] = *(uint4*)(res);
            dst[1] = *(uint4*)(res + 4);
        }
    }
}

extern "C" void kernel_launch(void* const* d_in, const int* in_sizes, int n_in,
                              void* d_out, int out_size, void* d_ws, size_t ws_size,
                              hipStream_t stream) {
    const float* x_seq  = (const float*)d_in[0];
    const int*   ei     = (const int*)d_in[1];
    const float* gcn_w  = (const float*)d_in[5];
    const float* gcn_b  = (const float*)d_in[6];
    const float* conv_w = (const float*)d_in[7];
    const float* conv_b = (const float*)d_in[8];
    const float* proj_w = (const float*)d_in[9];
    const float* proj_b = (const float*)d_in[10];
    const float* head_w = (const float*)d_in[11];
    const float* head_b = (const float*)d_in[12];
    float* outp = (float*)d_out;

    char* ws = (char*)d_ws;
    size_t off = 0;
    auto alloc = [&](size_t bytes) { void* p = ws + off; off += (bytes + 255) & ~(size_t)255; return p; };
    // persistent
    float*          dinv   = (float*)alloc((size_t)TT * NN * 4);
    int*            rowptr = (int*)alloc((size_t)TT * (NN + 1) * 4);
    unsigned short* csr    = (unsigned short*)alloc((size_t)TT * EE * 2);
    unsigned short* hb0    = (unsigned short*)alloc((size_t)NP * HH * 2);
    unsigned short* hb1    = (unsigned short*)alloc((size_t)NP * HH * 2);
    unsigned short* hb2    = (unsigned short*)alloc((size_t)NP * HH * 2);
    unsigned short* hb3    = (unsigned short*)alloc((size_t)NP * HH * 2);
    unsigned short* xsD    = (unsigned short*)alloc((size_t)NP * FF * 2);
    unsigned short* Bpk    = (unsigned short*)alloc((size_t)384 * HH * 2);
    float*          Bf32   = (float*)alloc((size_t)384 * HH * 4);
    float*          biasT  = (float*)alloc(HH * 4);
    // transient B: encoder xs + z + hgAll + Bq
    size_t tb = off;
    unsigned short* xs12  = (unsigned short*)alloc((size_t)TT * NN * FF * 2);
    float*          z12   = (float*)alloc((size_t)TT * NP * FF * 4);
    unsigned short* hgAll = (unsigned short*)alloc((size_t)TT * NP * HH * 2);
    unsigned short* Bq    = (unsigned short*)alloc((size_t)48 * 16 * 64 * 8 * 2);
    float*          biasQ = (float*)alloc(256 * 4);
    size_t compute_end = off;
    // transient A: CSR-build scratch, aliased over transient B
    off = tb;
    int* gData = (int*)alloc((size_t)TT * WPT * CHE * 4);
    int* pcnt  = (int*)alloc((size_t)TT * WPT * NB * 4);
    int* pofs  = (int*)alloc((size_t)TT * WPT * NB * 4);
    int* bbase = (int*)alloc((size_t)TT * NB * 4);
    size_t csr_end = off;
    bool fastcsr = (csr_end <= ws_size && compute_end <= ws_size);

    if (fastcsr) {
        k_binA<<<TT * WPT, 512, 0, stream>>>(ei, gData, pcnt, pofs);
        k_bscan2<<<TT, 512, 0, stream>>>(pcnt, bbase, rowptr);
        k_placeB<<<TT * NB, 256, 0, stream>>>(gData, pcnt, pofs, bbase, rowptr, dinv, csr);
    } else {
        off = tb;
        int* cnt  = (int*)alloc((size_t)TT * NN * 4);
        int* wofs = (int*)alloc((size_t)TT * NN * 4);
        k_zero<<<(TT * NN + 255) / 256, 256, 0, stream>>>(cnt, TT * NN);
        k_count<<<(TT * EE + 255) / 256, 256, 0, stream>>>(ei, cnt);
        k_dinvF<<<(TT * NN + 255) / 256, 256, 0, stream>>>(cnt, dinv);
        k_scan<<<TT, 1024, 0, stream>>>(cnt, rowptr, wofs);
        k_place<<<(TT * EE + 255) / 256, 256, 0, stream>>>(ei, wofs, csr);
    }

    k_wprepB<<<193, 256, 0, stream>>>(conv_w, proj_w, conv_b, proj_b, Bpk, Bf32, biasT);
    k_tchain<<<129, 128, 0, stream>>>(Bf32, biasT, Bq, biasQ);

    // encoder front-end: xs, aggregation, all-step hg, then ONE composed gemm
    k_xs<<<(TT * NN + 255) / 256, 256, 0, stream>>>(x_seq, dinv, xs12);
    k_aggX<<<AGG_GRID, 256, 0, stream>>>(xs12, csr, rowptr, dinv, z12);
    k_hgA<<<HGA_GRID, 256, 0, stream>>>(z12, gcn_w, gcn_b, hgAll);
    k_gemmE<<<NP / 32, 512, 0, stream>>>(hgAll, Bq, biasQ, hb2, hb3);   // h10 -> hb2, h11 -> hb3

    // decoder: t=12 reuses z(t=11); later steps gather in-tile from xsD
    unsigned short* hbuf[4] = {hb0, hb1, hb2, hb3};
    const float* dinv11 = dinv + (size_t)(TT - 1) * NN;
    const int* rp11 = rowptr + (size_t)(TT - 1) * (NN + 1);
    const unsigned short* csr11 = csr + (size_t)(TT - 1) * EE;
    for (int t = TT; t < TT + HOR; t++) {
        const float* zt = (t == TT) ? (z12 + (size_t)(TT - 1) * NP * FF) : nullptr;
        k_gemmF2<<<NP / 16, 256, 0, stream>>>(hbuf[(t + 2) & 3], hbuf[(t + 3) & 3],
                                              zt, (t == TT) ? 0 : 1,
                                              gcn_w, gcn_b, Bpk, biasT, hbuf[t & 3],
                                              head_w, head_b, dinv11, rp11, csr11,
                                              xsD, outp + (size_t)(t - TT) * NN * CC);
    }
}

// Round 9
// 439.067 us; speedup vs baseline: 1.1360x; 1.1360x over previous
//
#include <hip/hip_runtime.h>

#define NN 20000
#define NP 20032   // padded rows
#define EE 320000
#define TT 12
#define HH 128
#define FF 16
#define CC 16
#define HOR 6

// binning-sort parameters (CSR build)
#define NB 313      // buckets of 64 dst nodes
#define WPT 84      // binning workgroups per timestep
#define CHE 3812    // edges per binning WG (ceil(EE/WPT) rounded to mult of 4)

#define AGG_GRID 1896   // 8 XCDs x 3 half-timesteps x 79 blocks

typedef __attribute__((ext_vector_type(8))) short short8;
typedef __attribute__((ext_vector_type(4))) float f32x4;

__device__ __forceinline__ float blo(unsigned int u) {
    union { float f; unsigned int i; } v; v.i = u << 16; return v.f;
}
__device__ __forceinline__ float bhi(unsigned int u) {
    union { float f; unsigned int i; } v; v.i = u & 0xffff0000u; return v.f;
}
__device__ __forceinline__ unsigned short f2b(float f) {
    union { float f; unsigned int i; } v; v.f = f;
    unsigned int x = v.i;
    return (unsigned short)((x + 0x7fffu + ((x >> 16) & 1u)) >> 16);
}
__device__ __forceinline__ unsigned int pck(float lo, float hi) {
    return ((unsigned int)f2b(hi) << 16) | f2b(lo);
}
__device__ __forceinline__ void addrow(float* acc, uint4 r) {
    acc[0] += blo(r.x); acc[1] += bhi(r.x);
    acc[2] += blo(r.y); acc[3] += bhi(r.y);
    acc[4] += blo(r.z); acc[5] += bhi(r.z);
    acc[6] += blo(r.w); acc[7] += bhi(r.w);
}

// ---------------- setup kernels ----------------
__global__ void k_zero(int* p, int n) {
    int i = blockIdx.x * 256 + threadIdx.x;
    if (i < n) p[i] = 0;
}

// ---- CSR build phase A: LDS counting-sort of each WG's chunk, coalesced write-out ----
__global__ __launch_bounds__(512) void k_binA(const int* __restrict__ ei,
                                              int* __restrict__ gData,
                                              int* __restrict__ pcnt,
                                              int* __restrict__ pofs) {
    int wg = blockIdx.x;
    int t = wg / WPT, w = wg - t * WPT;
    __shared__ int lcnt[NB];
    __shared__ int sm[512];
    __shared__ __align__(16) int elist[CHE];
    int tid = threadIdx.x;
    for (int i = tid; i < NB; i += 512) lcnt[i] = 0;
    __syncthreads();
    int e0 = w * CHE, e1 = min(EE, e0 + CHE);
    int total = e1 - e0;                       // always a multiple of 4
    const int* si = ei + (size_t)t * 2 * EE;
    const int* di = si + EE;
    int eA = e0 + tid * 4, eB = eA + 2048;
    bool hA = eA < e1, hB = eB < e1;
    int sA[4], dA[4], pA[4], sB[4], dB[4], pB[4];
    if (hA) {
        int4 s4 = *(const int4*)(si + eA);
        int4 d4 = *(const int4*)(di + eA);
        sA[0] = s4.x; sA[1] = s4.y; sA[2] = s4.z; sA[3] = s4.w;
        dA[0] = d4.x; dA[1] = d4.y; dA[2] = d4.z; dA[3] = d4.w;
    }
    if (hB) {
        int4 s4 = *(const int4*)(si + eB);
        int4 d4 = *(const int4*)(di + eB);
        sB[0] = s4.x; sB[1] = s4.y; sB[2] = s4.z; sB[3] = s4.w;
        dB[0] = d4.x; dB[1] = d4.y; dB[2] = d4.z; dB[3] = d4.w;
    }
    if (hA) {
#pragma unroll
        for (int k = 0; k < 4; k++) pA[k] = atomicAdd(&lcnt[dA[k] >> 6], 1);
    }
    if (hB) {
#pragma unroll
        for (int k = 0; k < 4; k++) pB[k] = atomicAdd(&lcnt[dB[k] >> 6], 1);
    }
    __syncthreads();
    sm[tid] = (tid < NB) ? lcnt[tid] : 0;
    __syncthreads();
    for (int off = 1; off < 512; off <<= 1) {
        int u = (tid >= off) ? sm[tid - off] : 0;
        __syncthreads();
        sm[tid] += u;
        __syncthreads();
    }
    if (tid < NB) {
        int v = lcnt[tid];
        int ex = sm[tid] - v;
        size_t o = (size_t)(t * WPT + w) * NB + tid;
        pcnt[o] = v;
        pofs[o] = ex;
        sm[tid] = ex;      // sm now holds exclusive bucket offsets
    }
    __syncthreads();
    if (hA) {
#pragma unroll
        for (int k = 0; k < 4; k++) {
            int b = dA[k] >> 6;
            elist[sm[b] + pA[k]] = ((dA[k] & 63) << 16) | sA[k];
        }
    }
    if (hB) {
#pragma unroll
        for (int k = 0; k < 4; k++) {
            int b = dB[k] >> 6;
            elist[sm[b] + pB[k]] = ((dB[k] & 63) << 16) | sB[k];
        }
    }
    __syncthreads();
    int* gOut = gData + (size_t)(t * WPT + w) * CHE;
    for (int i = tid * 4; i < total; i += 2048)
        *(int4*)(gOut + i) = *(const int4*)&elist[i];
}

// ---- fused bucket-sum + exclusive scan per timestep ----
__global__ __launch_bounds__(512) void k_bscan2(const int* __restrict__ pcnt,
                                                int* __restrict__ bbase,
                                                int* __restrict__ rowptr) {
    int t = blockIdx.x, tid = threadIdx.x;
    __shared__ int sm[512];
    int v = 0;
    if (tid < NB)
        for (int w = 0; w < WPT; w++) v += pcnt[(size_t)(t * WPT + w) * NB + tid];
    sm[tid] = v;
    __syncthreads();
    for (int off = 1; off < 512; off <<= 1) {
        int u = (tid >= off) ? sm[tid - off] : 0;
        __syncthreads();
        sm[tid] += u;
        __syncthreads();
    }
    if (tid < NB) bbase[t * NB + tid] = sm[tid] - v;
    if (tid == 511) rowptr[(size_t)t * (NN + 1) + NN] = sm[511];
}

__global__ __launch_bounds__(256) void k_placeB(const int* __restrict__ gData,
                                                const int* __restrict__ pcnt,
                                                const int* __restrict__ pofs,
                                                const int* __restrict__ bbase,
                                                int* __restrict__ rowptr,
                                                float* __restrict__ dinv,
                                                unsigned short* __restrict__ csr) {
    int t = blockIdx.x / NB, b = blockIdx.x - t * NB;
    int tid = threadIdx.x;
    __shared__ int scnt[WPT], sofs[WPT], cofs[WPT + 1];
    __shared__ int elist[2048];
    __shared__ int cnt64[64], lofs[64], place[64];
    if (tid < WPT) {
        size_t o = (size_t)(t * WPT + tid) * NB + b;
        scnt[tid] = pcnt[o];
        sofs[tid] = pofs[o];
    }
    if (tid < 64) cnt64[tid] = 0;
    __syncthreads();
    if (tid == 0) {
        int s = 0;
        for (int w = 0; w < WPT; w++) { cofs[w] = s; s += scnt[w]; }
        cofs[WPT] = s;
    }
    __syncthreads();
    int total = cofs[WPT];
    int wv = tid >> 6, lane = tid & 63;
    for (int w = wv; w < WPT; w += 4) {
        int c = scnt[w], o = cofs[w];
        const int* sp = gData + (size_t)(t * WPT + w) * CHE + sofs[w];
        for (int i = lane; i < c; i += 64) elist[o + i] = sp[i];
    }
    __syncthreads();
    for (int i = tid; i < total; i += 256) atomicAdd(&cnt64[elist[i] >> 16], 1);
    __syncthreads();
    if (tid == 0) {
        int s = 0;
        for (int j = 0; j < 64; j++) { lofs[j] = s; place[j] = s; s += cnt64[j]; }
    }
    __syncthreads();
    int base = bbase[t * NB + b];
    int n = b * 64 + tid;
    if (tid < 64 && n < NN) {
        rowptr[(size_t)t * (NN + 1) + n] = base + lofs[tid];
        dinv[(size_t)t * NN + n] = rsqrtf(1.0f + (float)cnt64[tid]);
    }
    unsigned short* cbase = csr + (size_t)t * EE + base;
    for (int i = tid; i < total; i += 256) {
        int en = elist[i];
        int r = atomicAdd(&place[en >> 16], 1);
        cbase[r] = (unsigned short)(en & 0xffff);
    }
}

// ---------------- fallback CSR build (small ws_size) ----------------
__global__ void k_count(const int* __restrict__ ei, int* __restrict__ cnt) {
    int idx = blockIdx.x * 256 + threadIdx.x;
    if (idx >= TT * EE) return;
    int t = idx / EE, e = idx - t * EE;
    int d = ei[t * 2 * EE + EE + e];
    atomicAdd(&cnt[t * NN + d], 1);
}

__global__ void k_dinvF(const int* __restrict__ cnt, float* __restrict__ dinv) {
    int idx = blockIdx.x * 256 + threadIdx.x;
    if (idx >= TT * NN) return;
    dinv[idx] = 1.0f / sqrtf(1.0f + (float)cnt[idx]);
}

__global__ void k_scan(const int* __restrict__ cnt, int* __restrict__ rowptr, int* __restrict__ wofs) {
    int t = blockIdx.x;
    const int* c = cnt + t * NN;
    int* rp = rowptr + t * (NN + 1);
    int* wo = wofs + t * NN;
    __shared__ int sums[1024];
    int tid = threadIdx.x;
    const int CH2 = 20;
    int base = tid * CH2;
    int loc[CH2];
    int s = 0;
    for (int i = 0; i < CH2; i++) { int ix = base + i; int v = (ix < NN) ? c[ix] : 0; loc[i] = s; s += v; }
    sums[tid] = s;
    __syncthreads();
    for (int off = 1; off < 1024; off <<= 1) {
        int v = (tid >= off) ? sums[tid - off] : 0;
        __syncthreads();
        sums[tid] += v;
        __syncthreads();
    }
    int excl = (tid > 0) ? sums[tid - 1] : 0;
    for (int i = 0; i < CH2; i++) {
        int ix = base + i;
        if (ix < NN) { int e = excl + loc[i]; rp[ix] = e; wo[ix] = e; }
    }
    if (tid == 1023) rp[NN] = sums[1023];
}

__global__ void k_place(const int* __restrict__ ei, int* __restrict__ wofs,
                        unsigned short* __restrict__ csr) {
    int idx = blockIdx.x * 256 + threadIdx.x;
    if (idx >= TT * EE) return;
    int t = idx / EE, e = idx - t * EE;
    int s = ei[t * 2 * EE + e];
    int d = ei[t * 2 * EE + EE + e];
    int pos = atomicAdd(&wofs[t * NN + d], 1);
    csr[t * EE + pos] = (unsigned short)s;
}

// ---------------- fused TCN+proj weight prep (+ bias block) ----------------
// Bf32[384][128]: rows 0-127 = M2 (coeff of h_{t-2}), 128-255 = M1 (h_{t-1}),
// 256-383 = Mh (hg_t). Bpk = MFMA-packed single-step B for the decoder.
__global__ void k_wprepB(const float* __restrict__ cw, const float* __restrict__ pw,
                         const float* __restrict__ cb, const float* __restrict__ pb,
                         unsigned short* __restrict__ Bpk, float* __restrict__ Bf32,
                         float* __restrict__ bias) {
    int idx = blockIdx.x * 256 + threadIdx.x;
    if (blockIdx.x == 192) {
        int h = threadIdx.x;
        if (h < HH) {
            float m = pb[h];
            for (int d = 0; d < 3; d++)
                for (int o = 0; o < HH; o++)
                    m += cb[d * HH + o] * pw[h * 384 + d * HH + o];
            bias[h] = m;
        }
        return;
    }
    if (idx >= 384 * HH) return;
    int kk = idx / HH, h = idx - kk * HH;
    float m = 0.f;
    if (kk < 128) {
        int i = kk;
        for (int o = 0; o < HH; o++)
            m += cw[((1 * HH + o) * HH + i) * 3 + 0] * pw[h * 384 + 128 + o];
    } else if (kk < 256) {
        int i = kk - 128;
        for (int o = 0; o < HH; o++)
            m += cw[((0 * HH + o) * HH + i) * 3 + 0] * pw[h * 384 + o];
    } else {
        int i = kk - 256;
        for (int d = 0; d < 3; d++)
            for (int o = 0; o < HH; o++)
                m += cw[((d * HH + o) * HH + i) * 3 + 1] * pw[h * 384 + d * HH + o];
    }
    Bf32[kk * HH + h] = m;
    int ki = kk >> 5, r = kk & 31, q = r >> 3, j = r & 7, nt = h >> 4, ln = q * 16 + (h & 15);
    Bpk[(size_t)((ki * 8 + nt) * 64 + ln) * 8 + j] = f2b(m);
}

// ---------------- encoder collapse: T-chain weight build ----------------
// h_t = h_{t-2}M2 + h_{t-1}M1 + hg_t Mh + b  (linear in hg_s). Decoder needs
// only h_10, h_11:  h_10 = sum_s hg_s T_{10-s} + P_10 ; h_11 analogous.
// T_0 = Mh, T_j = T_{j-1}M1 + T_{j-2}M2 ; P_0 = b, P_j = P_{j-1}M1 + P_{j-2}M2 + b.
__global__ __launch_bounds__(128) void k_tchain(const float* __restrict__ Bf32,
                                                const float* __restrict__ biasT,
                                                unsigned short* __restrict__ Bq,
                                                float* __restrict__ biasQ) {
    __shared__ float v1[128], v2[128];
    int c = threadIdx.x;
    int r = blockIdx.x;
    const float* M2 = Bf32;
    const float* M1 = Bf32 + 128 * HH;
    const float* Mh = Bf32 + 256 * HH;
    if (r < 128) {
        int q4 = (r & 31) >> 3, jj = r & 7, rb = r >> 5;
        v1[c] = Mh[r * HH + c];     // T_0 row r
        v2[c] = 0.f;                // T_{-1}
        __syncthreads();
        // write T_0: half0 at s=10, half1 at s=11
        {
            float val = v1[c];
            int kb0 = 10 * 4 + rb, nt0 = c >> 4, ln = q4 * 16 + (c & 15);
            Bq[((size_t)(kb0 * 16 + nt0) * 64 + ln) * 8 + jj] = f2b(val);
            int kb1 = 11 * 4 + rb, nt1 = 8 + (c >> 4);
            Bq[((size_t)(kb1 * 16 + nt1) * 64 + ln) * 8 + jj] = f2b(val);
        }
        for (int j = 1; j < 12; j++) {
            float acc = 0.f;
            for (int k = 0; k < 128; k++)
                acc += v1[k] * M1[k * HH + c] + v2[k] * M2[k * HH + c];
            __syncthreads();
            v2[c] = v1[c]; v1[c] = acc;
            __syncthreads();
            int ln = q4 * 16 + (c & 15);
            if (j <= 10) {      // half0 (h_10): s = 10-j
                int kb = (10 - j) * 4 + rb, nt = c >> 4;
                Bq[((size_t)(kb * 16 + nt) * 64 + ln) * 8 + jj] = f2b(acc);
            }
            {                   // half1 (h_11): s = 11-j
                int kb = (11 - j) * 4 + rb, nt = 8 + (c >> 4);
                Bq[((size_t)(kb * 16 + nt) * 64 + ln) * 8 + jj] = f2b(acc);
            }
        }
        // zero-fill half0 of slice s=11 (h_10 has no hg_11 term)
        {
            int kb = 11 * 4 + rb, nt = c >> 4, ln = q4 * 16 + (c & 15);
            Bq[((size_t)(kb * 16 + nt) * 64 + ln) * 8 + jj] = 0;
        }
    } else {
        // bias chain: after loop v2 = P_10, v1 = P_11
        v1[c] = biasT[c];
        v2[c] = 0.f;
        __syncthreads();
        for (int j = 1; j < 12; j++) {
            float acc = biasT[c];
            for (int k = 0; k < 128; k++)
                acc += v1[k] * M1[k * HH + c] + v2[k] * M2[k * HH + c];
            __syncthreads();
            v2[c] = v1[c]; v1[c] = acc;
            __syncthreads();
        }
        biasQ[c] = v2[c];
        biasQ[128 + c] = v1[c];
    }
}

// ---------------- encoder front-end ----------------
__global__ void k_xs(const float* __restrict__ x, const float* __restrict__ dinv,
                     unsigned short* __restrict__ xs) {
    int idx = blockIdx.x * 256 + threadIdx.x;
    if (idx >= TT * NN) return;
    float dn = dinv[idx];
    const float4* xr = (const float4*)(x + (size_t)idx * FF);
    unsigned int res[8];
#pragma unroll
    for (int k = 0; k < 4; k++) {
        float4 v = xr[k];
        res[2 * k]     = pck(v.x * dn, v.y * dn);
        res[2 * k + 1] = pck(v.z * dn, v.w * dn);
    }
    uint4* dst = (uint4*)(xs + (size_t)idx * FF);
    dst[0] = *(uint4*)(res);
    dst[1] = *(uint4*)(res + 4);
}

// XCD-affinity aggregation (kept from R7: -20us vs round-robin).
__global__ __launch_bounds__(256) void k_aggX(const unsigned short* __restrict__ xsA,
                                              const unsigned short* __restrict__ csrA,
                                              const int* __restrict__ rpA,
                                              const float* __restrict__ dinvA,
                                              float* __restrict__ zA) {
    int bid = blockIdx.x;
    int x = bid & 7, k = bid >> 3;           // target XCD, slot 0..236
    int h = 3 * x + k / 79;                  // half-timestep 0..23
    int g = h >> 1;                          // timestep
    int nb = (h & 1) * 79 + (k % 79);        // 128-row block within timestep
    int tid = threadIdx.x;
    int r = tid >> 1, eo = tid & 1;          // 2 threads per row
    int n = nb * 128 + r;
    if (n >= NN) return;
    const unsigned short* xs = xsA + (size_t)g * NN * FF;
    const unsigned short* csr = csrA + (size_t)g * EE;
    const int* rp = rpA + (size_t)g * (NN + 1);
    float acc[16];
#pragma unroll
    for (int i = 0; i < 16; i++) acc[i] = 0.f;
    int j0 = rp[n], j1 = rp[n + 1];
    int j = j0 + eo;
    for (; j + 2 < j1; j += 4) {
        int s0 = csr[j], s1 = csr[j + 2];
        const uint4* p0 = (const uint4*)(xs + (size_t)s0 * FF);
        const uint4* p1 = (const uint4*)(xs + (size_t)s1 * FF);
        uint4 a0 = p0[0], a1 = p0[1], b0 = p1[0], b1 = p1[1];
        addrow(acc, a0); addrow(acc + 8, a1);
        addrow(acc, b0); addrow(acc + 8, b1);
    }
    if (j < j1) {
        const uint4* p0 = (const uint4*)(xs + (size_t)csr[j] * FF);
        uint4 a0 = p0[0], a1 = p0[1];
        addrow(acc, a0); addrow(acc + 8, a1);
    }
#pragma unroll
    for (int i = 0; i < 16; i++) acc[i] += __shfl_xor(acc[i], 1);
    if (eo == 0) {
        const uint4* sp = (const uint4*)(xs + (size_t)n * FF);
        uint4 a = sp[0], b4 = sp[1];
        addrow(acc, a); addrow(acc + 8, b4);
        float dn = dinvA[(size_t)g * NN + n];
        float4* zo = (float4*)(zA + (size_t)g * NP * FF + (size_t)n * FF);
#pragma unroll
        for (int k2 = 0; k2 < 4; k2++)
            zo[k2] = make_float4(acc[4 * k2] * dn, acc[4 * k2 + 1] * dn,
                                 acc[4 * k2 + 2] * dn, acc[4 * k2 + 3] * dn);
    }
}

// ---------------- ONE fused encoder gemm: [h10|h11] = sum_s relu(z_s Wg+gb) * T + P ----------------
// R9: hg computed INLINE per K-slice (R8's k_hgA materialized 60MB hgAll -> 73us
// latency-bound producer; fusing removes the 120MB round-trip and the launch).
// 626 blocks x 512 thr (8 waves: 2 row-groups x 4 col-groups). Per s: compute
// 32x128 hg slice in LDS (512 thr x 8 outs), barrier, 4 MFMA kb-steps, barrier.
__global__ __launch_bounds__(512) void k_gemmE(const float* __restrict__ z12,
                                               const float* __restrict__ gw,
                                               const float* __restrict__ gb,
                                               const unsigned short* __restrict__ Bq,
                                               const float* __restrict__ biasQ,
                                               unsigned short* __restrict__ out0,
                                               unsigned short* __restrict__ out1) {
    __shared__ float Wg[FF * HH];
    __shared__ float gbs[HH];
    __shared__ float bqs[256];
    __shared__ __align__(16) unsigned short hgs[32 * 136];
    __shared__ __align__(16) unsigned short csh[32 * 264];
    int tid = threadIdx.x;
    int wid = tid >> 6, lane = tid & 63;
    int rg = wid & 1, cg = wid >> 1;
    int m0b = blockIdx.x * 32;
    int mr = lane & 15, q = lane >> 4;
    for (int i = tid; i < FF * HH; i += 512) Wg[i] = gw[i];
    if (tid < HH) gbs[tid] = gb[tid];
    if (tid >= 256 && tid < 512) bqs[tid - 256] = biasQ[tid - 256];
    __syncthreads();
    int nt0 = cg * 4;
    int hrow = tid >> 4, hc0 = (tid & 15) * 8;      // hg-producer role
    f32x4 acc[4];
#pragma unroll
    for (int j = 0; j < 4; j++) acc[j] = (f32x4){0.f, 0.f, 0.f, 0.f};
    for (int s = 0; s < 12; s++) {
        // --- produce hg slice s for rows m0b..m0b+31 into LDS ---
        {
            const float4* zp = (const float4*)(z12 + ((size_t)s * NP + m0b + hrow) * FF);
            float4 z0 = zp[0], z1 = zp[1], z2 = zp[2], z3 = zp[3];
            float zr[16] = {z0.x, z0.y, z0.z, z0.w, z1.x, z1.y, z1.z, z1.w,
                            z2.x, z2.y, z2.z, z2.w, z3.x, z3.y, z3.z, z3.w};
            float sv[8];
#pragma unroll
            for (int c = 0; c < 8; c++) sv[c] = gbs[hc0 + c];
#pragma unroll
            for (int f = 0; f < 16; f++) {
                const float4* wp = (const float4*)(Wg + f * HH + hc0);
                float4 w0 = wp[0], w1 = wp[1];
                float zf = zr[f];
                sv[0] += zf * w0.x; sv[1] += zf * w0.y; sv[2] += zf * w0.z; sv[3] += zf * w0.w;
                sv[4] += zf * w1.x; sv[5] += zf * w1.y; sv[6] += zf * w1.z; sv[7] += zf * w1.w;
            }
            unsigned int res[4];
#pragma unroll
            for (int k = 0; k < 4; k++)
                res[k] = pck(fmaxf(sv[2 * k], 0.f), fmaxf(sv[2 * k + 1], 0.f));
            *(uint4*)&hgs[hrow * 136 + hc0] = *(uint4*)res;
        }
        __syncthreads();
        // --- consume: 4 kb-steps of MFMA ---
#pragma unroll
        for (int k2 = 0; k2 < 4; k2++) {
            int kb = s * 4 + k2;
            short8 bf[4];
#pragma unroll
            for (int j = 0; j < 4; j++)
                bf[j] = *(const short8*)(Bq + ((size_t)(kb * 16 + nt0 + j) * 64 + lane) * 8);
            short8 af = *(const short8*)&hgs[(rg * 16 + mr) * 136 + k2 * 32 + q * 8];
#pragma unroll
            for (int j = 0; j < 4; j++)
                acc[j] = __builtin_amdgcn_mfma_f32_16x16x32_bf16(af, bf[j], acc[j], 0, 0, 0);
        }
        __syncthreads();
    }
#pragma unroll
    for (int j = 0; j < 4; j++) {
        int c = (nt0 + j) * 16 + mr;
        float bv = bqs[c];
#pragma unroll
        for (int r = 0; r < 4; r++)
            csh[(rg * 16 + q * 4 + r) * 264 + c] = f2b(acc[j][r] + bv);
    }
    __syncthreads();
#pragma unroll
    for (int i = 0; i < 2; i++) {
        int idx = i * 512 + tid;        // 0..1023: 32 rows x 32 chunks
        int row = idx >> 5, c8 = (idx & 31) * 8;
        short8 v = *(const short8*)&csh[row * 264 + c8];
        if (c8 < 128) *(short8*)(out0 + (size_t)(m0b + row) * HH + c8) = v;
        else          *(short8*)(out1 + (size_t)(m0b + row) * HH + (c8 - 128)) = v;
    }
}

// hg A-fragment (decoder): lane computes 32 hg values for row mr of a 16-row block
__device__ __forceinline__ void hg_frag(const float* zsh, const float* Wg, const float* gbs,
                                        int mr, int q, short8* hgf) {
    float zr[16];
    {
        const float4* zp = (const float4*)(zsh + mr * FF);
        float4 z0 = zp[0], z1 = zp[1], z2 = zp[2], z3 = zp[3];
        zr[0] = z0.x; zr[1] = z0.y; zr[2] = z0.z; zr[3] = z0.w;
        zr[4] = z1.x; zr[5] = z1.y; zr[6] = z1.z; zr[7] = z1.w;
        zr[8] = z2.x; zr[9] = z2.y; zr[10] = z2.z; zr[11] = z2.w;
        zr[12] = z3.x; zr[13] = z3.y; zr[14] = z3.z; zr[15] = z3.w;
    }
#pragma unroll
    for (int k2 = 0; k2 < 4; k2++) {
        float s[8];
#pragma unroll
        for (int c = 0; c < 8; c++) s[c] = gbs[k2 * 32 + q * 8 + c];
#pragma unroll
        for (int f = 0; f < 16; f++) {
            const float4* wp = (const float4*)(Wg + f * HH + k2 * 32 + q * 8);
            float4 w0 = wp[0], w1 = wp[1];
            float zf = zr[f];
            s[0] += zf * w0.x; s[1] += zf * w0.y; s[2] += zf * w0.z; s[3] += zf * w0.w;
            s[4] += zf * w1.x; s[5] += zf * w1.y; s[6] += zf * w1.z; s[7] += zf * w1.w;
        }
#pragma unroll
        for (int c = 0; c < 8; c++) hgf[k2][c] = (short)f2b(fmaxf(s[c], 0.f));
    }
}

// ---------------- decoder fused step: [gather] + gemm + head + feedback ----------------
// 16-row blocks, 4 waves x (16 rows x 32 cols). (unchanged from R6/R7)
__global__ __launch_bounds__(256, 3) void k_gemmF2(const unsigned short* __restrict__ a0,
                                                   const unsigned short* __restrict__ a1,
                                                   const float* __restrict__ zt, int gather,
                                                   const float* __restrict__ gw,
                                                   const float* __restrict__ gb,
                                                   const unsigned short* __restrict__ Bpk,
                                                   const float* __restrict__ bias,
                                                   unsigned short* __restrict__ out,
                                                   const float* __restrict__ hw,
                                                   const float* __restrict__ hbv,
                                                   const float* __restrict__ dinvN,
                                                   const int* __restrict__ rp,
                                                   const unsigned short* __restrict__ csr,
                                                   unsigned short* __restrict__ xsD,
                                                   float* __restrict__ yout) {
    __shared__ float Wg[FF * HH];
    __shared__ float Whs[CC * 132];     // padded: kills 16-way head bank conflict
    __shared__ float gbs[HH], biasS[HH], hbS[CC];
    __shared__ float zsh[16 * FF];
    __shared__ __align__(16) unsigned short hgD[16 * 136];
    __shared__ unsigned short hsh[16 * 136];
    __shared__ float ysh[16 * 17];
    int tid = threadIdx.x;
    int wid = tid >> 6, lane = tid & 63;
    int m0b = blockIdx.x * 16;
    int mr = lane & 15, q = lane >> 4;
    for (int i = tid; i < FF * HH; i += 256) {
        Wg[i] = gw[i];
        Whs[(i >> 7) * 132 + (i & 127)] = hw[i];
    }
    if (tid < HH) { gbs[tid] = gb[tid]; biasS[tid] = bias[tid]; }
    if (tid < CC) hbS[tid] = hbv[tid];
    if (!gather) {
        if (tid < 16 * FF) zsh[tid] = zt[(size_t)m0b * FF + tid];
    } else {
        // in-tile 16-dim aggregation from xsD: 16 threads/row (2 halves x 8-way edges)
        int r = tid >> 4, p = tid & 15, half = p & 1, eo = p >> 1;
        int n = m0b + r;
        float a[8];
#pragma unroll
        for (int k = 0; k < 8; k++) a[k] = 0.f;
        if (n < NN) {
            int j0 = rp[n], j1 = rp[n + 1];
            for (int j = j0 + eo; j < j1; j += 8) {
                int s = csr[j];
                uint4 v = *(const uint4*)(xsD + (size_t)s * FF + half * 8);
                addrow(a, v);
            }
        }
#pragma unroll
        for (int k = 0; k < 8; k++) {
            a[k] += __shfl_xor(a[k], 2);
            a[k] += __shfl_xor(a[k], 4);
            a[k] += __shfl_xor(a[k], 8);
        }
        if (n < NN && eo == 0) {
            uint4 sv = *(const uint4*)(xsD + (size_t)n * FF + half * 8);
            addrow(a, sv);
            float dn = dinvN[n];
#pragma unroll
            for (int k = 0; k < 8; k++) zsh[r * FF + half * 8 + k] = a[k] * dn;
        }
    }
    __syncthreads();
    if (wid == 0) {
        short8 hgf[4];
        hg_frag(zsh, Wg, gbs, mr, q, hgf);
#pragma unroll
        for (int k2 = 0; k2 < 4; k2++)
            *(short8*)&hgD[mr * 136 + k2 * 32 + q * 8] = hgf[k2];
    }
    __syncthreads();
    int nt0 = wid * 2;                  // wave's 2 col tiles (32 cols)
    f32x4 acc[2];
#pragma unroll
    for (int j = 0; j < 2; j++) acc[j] = (f32x4){0.f, 0.f, 0.f, 0.f};
#pragma unroll
    for (int ki = 0; ki < 12; ki++) {
        short8 bf[2];
#pragma unroll
        for (int j = 0; j < 2; j++)
            bf[j] = *(const short8*)(Bpk + (size_t)((ki * 8 + nt0 + j) * 64 + lane) * 8);
        short8 af;
        if (ki < 4)
            af = *(const short8*)(a0 + (size_t)(m0b + mr) * HH + ki * 32 + q * 8);
        else if (ki < 8)
            af = *(const short8*)(a1 + (size_t)(m0b + mr) * HH + (ki - 4) * 32 + q * 8);
        else
            af = *(const short8*)&hgD[mr * 136 + (ki - 8) * 32 + q * 8];
#pragma unroll
        for (int j = 0; j < 2; j++)
            acc[j] = __builtin_amdgcn_mfma_f32_16x16x32_bf16(af, bf[j], acc[j], 0, 0, 0);
    }
#pragma unroll
    for (int j = 0; j < 2; j++) {
        int feat = (nt0 + j) * 16 + mr;
        float bv = biasS[feat];
#pragma unroll
        for (int r = 0; r < 4; r++)
            hsh[(q * 4 + r) * 136 + feat] = f2b(acc[j][r] + bv);
    }
    __syncthreads();
    // coalesced h write-out (16B/lane): 16 rows x 16 chunks = 256
    {
        int row = tid >> 4, c8 = (tid & 15) * 8;
        *(short8*)(out + (size_t)(m0b + row) * HH + c8) =
            *(const short8*)&hsh[row * 136 + c8];
    }
    // head: y[n][c] = hb[c] + sum_k h[n][k]*Wh[c][k]; 1 thread per (row, col)
    {
        int r = tid >> 4, c = tid & 15;
        float y = hbS[c];
        for (int k = 0; k < HH; k++)
            y += blo((unsigned int)hsh[r * 136 + k]) * Whs[c * 132 + k];
        ysh[r * 17 + c] = y;
        int gn = m0b + r;
        if (gn < NN) yout[(size_t)gn * CC + c] = y;
    }
    __syncthreads();
    // next-step xs: xsD[n][k] = bf16(y[n][k] * dinv[n])
    if (tid < 16) {
        int gn = m0b + tid;
        if (gn < NN) {
            float dn = dinvN[gn];
            unsigned int res[8];
#pragma unroll
            for (int k = 0; k < 8; k++)
                res[k] = pck(ysh[tid * 17 + 2 * k] * dn, ysh[tid * 17 + 2 * k + 1] * dn);
            uint4* dst = (uint4*)(xsD + (size_t)gn * FF);
            dst[0] = *(uint4*)(res);
            dst[1] = *(uint4*)(res + 4);
        }
    }
}

extern "C" void kernel_launch(void* const* d_in, const int* in_sizes, int n_in,
                              void* d_out, int out_size, void* d_ws, size_t ws_size,
                              hipStream_t stream) {
    const float* x_seq  = (const float*)d_in[0];
    const int*   ei     = (const int*)d_in[1];
    const float* gcn_w  = (const float*)d_in[5];
    const float* gcn_b  = (const float*)d_in[6];
    const float* conv_w = (const float*)d_in[7];
    const float* conv_b = (const float*)d_in[8];
    const float* proj_w = (const float*)d_in[9];
    const float* proj_b = (const float*)d_in[10];
    const float* head_w = (const float*)d_in[11];
    const float* head_b = (const float*)d_in[12];
    float* outp = (float*)d_out;

    char* ws = (char*)d_ws;
    size_t off = 0;
    auto alloc = [&](size_t bytes) { void* p = ws + off; off += (bytes + 255) & ~(size_t)255; return p; };
    // persistent
    float*          dinv   = (float*)alloc((size_t)TT * NN * 4);
    int*            rowptr = (int*)alloc((size_t)TT * (NN + 1) * 4);
    unsigned short* csr    = (unsigned short*)alloc((size_t)TT * EE * 2);
    unsigned short* hb0    = (unsigned short*)alloc((size_t)NP * HH * 2);
    unsigned short* hb1    = (unsigned short*)alloc((size_t)NP * HH * 2);
    unsigned short* hb2    = (unsigned short*)alloc((size_t)NP * HH * 2);
    unsigned short* hb3    = (unsigned short*)alloc((size_t)NP * HH * 2);
    unsigned short* xsD    = (unsigned short*)alloc((size_t)NP * FF * 2);
    unsigned short* Bpk    = (unsigned short*)alloc((size_t)384 * HH * 2);
    float*          Bf32   = (float*)alloc((size_t)384 * HH * 4);
    float*          biasT  = (float*)alloc(HH * 4);
    // transient B: encoder xs + z + Bq
    size_t tb = off;
    unsigned short* xs12  = (unsigned short*)alloc((size_t)TT * NN * FF * 2);
    float*          z12   = (float*)alloc((size_t)TT * NP * FF * 4);
    unsigned short* Bq    = (unsigned short*)alloc((size_t)48 * 16 * 64 * 8 * 2);
    float*          biasQ = (float*)alloc(256 * 4);
    size_t compute_end = off;
    // transient A: CSR-build scratch, aliased over transient B
    off = tb;
    int* gData = (int*)alloc((size_t)TT * WPT * CHE * 4);
    int* pcnt  = (int*)alloc((size_t)TT * WPT * NB * 4);
    int* pofs  = (int*)alloc((size_t)TT * WPT * NB * 4);
    int* bbase = (int*)alloc((size_t)TT * NB * 4);
    size_t csr_end = off;
    bool fastcsr = (csr_end <= ws_size && compute_end <= ws_size);

    if (fastcsr) {
        k_binA<<<TT * WPT, 512, 0, stream>>>(ei, gData, pcnt, pofs);
        k_bscan2<<<TT, 512, 0, stream>>>(pcnt, bbase, rowptr);
        k_placeB<<<TT * NB, 256, 0, stream>>>(gData, pcnt, pofs, bbase, rowptr, dinv, csr);
    } else {
        off = tb;
        int* cnt  = (int*)alloc((size_t)TT * NN * 4);
        int* wofs = (int*)alloc((size_t)TT * NN * 4);
        k_zero<<<(TT * NN + 255) / 256, 256, 0, stream>>>(cnt, TT * NN);
        k_count<<<(TT * EE + 255) / 256, 256, 0, stream>>>(ei, cnt);
        k_dinvF<<<(TT * NN + 255) / 256, 256, 0, stream>>>(cnt, dinv);
        k_scan<<<TT, 1024, 0, stream>>>(cnt, rowptr, wofs);
        k_place<<<(TT * EE + 255) / 256, 256, 0, stream>>>(ei, wofs, csr);
    }

    k_wprepB<<<193, 256, 0, stream>>>(conv_w, proj_w, conv_b, proj_b, Bpk, Bf32, biasT);
    k_tchain<<<129, 128, 0, stream>>>(Bf32, biasT, Bq, biasQ);

    // encoder front-end: xs, aggregation, then ONE fused hg+composed gemm
    k_xs<<<(TT * NN + 255) / 256, 256, 0, stream>>>(x_seq, dinv, xs12);
    k_aggX<<<AGG_GRID, 256, 0, stream>>>(xs12, csr, rowptr, dinv, z12);
    k_gemmE<<<NP / 32, 512, 0, stream>>>(z12, gcn_w, gcn_b, Bq, biasQ, hb2, hb3);   // h10 -> hb2, h11 -> hb3

    // decoder: t=12 reuses z(t=11); later steps gather in-tile from xsD
    unsigned short* hbuf[4] = {hb0, hb1, hb2, hb3};
    const float* dinv11 = dinv + (size_t)(TT - 1) * NN;
    const int* rp11 = rowptr + (size_t)(TT - 1) * (NN + 1);
    const unsigned short* csr11 = csr + (size_t)(TT - 1) * EE;
    for (int t = TT; t < TT + HOR; t++) {
        const float* zt = (t == TT) ? (z12 + (size_t)(TT - 1) * NP * FF) : nullptr;
        k_gemmF2<<<NP / 16, 256, 0, stream>>>(hbuf[(t + 2) & 3], hbuf[(t + 3) & 3],
                                              zt, (t == TT) ? 0 : 1,
                                              gcn_w, gcn_b, Bpk, biasT, hbuf[t & 3],
                                              head_w, head_b, dinv11, rp11, csr11,
                                              xsD, outp + (size_t)(t - TT) * NN * CC);
    }
}

// Round 10
// 436.658 us; speedup vs baseline: 1.1423x; 1.0055x over previous
//
#include <hip/hip_runtime.h>

#define NN 20000
#define NP 20032   // padded rows
#define EE 320000
#define TT 12
#define HH 128
#define FF 16
#define CC 16
#define HOR 6

// binning-sort parameters (CSR build)
#define NB 313      // buckets of 64 dst nodes
#define WPT 84      // binning workgroups per timestep
#define CHE 3812    // edges per binning WG (ceil(EE/WPT) rounded to mult of 4)

#define AGG_GRID 1896   // 8 XCDs x 3 half-timesteps x 79 blocks

typedef __attribute__((ext_vector_type(8))) short short8;
typedef __attribute__((ext_vector_type(4))) float f32x4;

__device__ __forceinline__ float blo(unsigned int u) {
    union { float f; unsigned int i; } v; v.i = u << 16; return v.f;
}
__device__ __forceinline__ float bhi(unsigned int u) {
    union { float f; unsigned int i; } v; v.i = u & 0xffff0000u; return v.f;
}
__device__ __forceinline__ unsigned short f2b(float f) {
    union { float f; unsigned int i; } v; v.f = f;
    unsigned int x = v.i;
    return (unsigned short)((x + 0x7fffu + ((x >> 16) & 1u)) >> 16);
}
__device__ __forceinline__ unsigned int pck(float lo, float hi) {
    return ((unsigned int)f2b(hi) << 16) | f2b(lo);
}
__device__ __forceinline__ void addrow(float* acc, uint4 r) {
    acc[0] += blo(r.x); acc[1] += bhi(r.x);
    acc[2] += blo(r.y); acc[3] += bhi(r.y);
    acc[4] += blo(r.z); acc[5] += bhi(r.z);
    acc[6] += blo(r.w); acc[7] += bhi(r.w);
}

// ---------------- setup kernels ----------------
__global__ void k_zero(int* p, int n) {
    int i = blockIdx.x * 256 + threadIdx.x;
    if (i < n) p[i] = 0;
}

// ---- CSR build phase A: LDS counting-sort of each WG's chunk, coalesced write-out ----
__global__ __launch_bounds__(512) void k_binA(const int* __restrict__ ei,
                                              int* __restrict__ gData,
                                              int* __restrict__ pcnt,
                                              int* __restrict__ pofs) {
    int wg = blockIdx.x;
    int t = wg / WPT, w = wg - t * WPT;
    __shared__ int lcnt[NB];
    __shared__ int sm[512];
    __shared__ __align__(16) int elist[CHE];
    int tid = threadIdx.x;
    for (int i = tid; i < NB; i += 512) lcnt[i] = 0;
    __syncthreads();
    int e0 = w * CHE, e1 = min(EE, e0 + CHE);
    int total = e1 - e0;                       // always a multiple of 4
    const int* si = ei + (size_t)t * 2 * EE;
    const int* di = si + EE;
    int eA = e0 + tid * 4, eB = eA + 2048;
    bool hA = eA < e1, hB = eB < e1;
    int sA[4], dA[4], pA[4], sB[4], dB[4], pB[4];
    if (hA) {
        int4 s4 = *(const int4*)(si + eA);
        int4 d4 = *(const int4*)(di + eA);
        sA[0] = s4.x; sA[1] = s4.y; sA[2] = s4.z; sA[3] = s4.w;
        dA[0] = d4.x; dA[1] = d4.y; dA[2] = d4.z; dA[3] = d4.w;
    }
    if (hB) {
        int4 s4 = *(const int4*)(si + eB);
        int4 d4 = *(const int4*)(di + eB);
        sB[0] = s4.x; sB[1] = s4.y; sB[2] = s4.z; sB[3] = s4.w;
        dB[0] = d4.x; dB[1] = d4.y; dB[2] = d4.z; dB[3] = d4.w;
    }
    if (hA) {
#pragma unroll
        for (int k = 0; k < 4; k++) pA[k] = atomicAdd(&lcnt[dA[k] >> 6], 1);
    }
    if (hB) {
#pragma unroll
        for (int k = 0; k < 4; k++) pB[k] = atomicAdd(&lcnt[dB[k] >> 6], 1);
    }
    __syncthreads();
    sm[tid] = (tid < NB) ? lcnt[tid] : 0;
    __syncthreads();
    for (int off = 1; off < 512; off <<= 1) {
        int u = (tid >= off) ? sm[tid - off] : 0;
        __syncthreads();
        sm[tid] += u;
        __syncthreads();
    }
    if (tid < NB) {
        int v = lcnt[tid];
        int ex = sm[tid] - v;
        size_t o = (size_t)(t * WPT + w) * NB + tid;
        pcnt[o] = v;
        pofs[o] = ex;
        sm[tid] = ex;      // sm now holds exclusive bucket offsets
    }
    __syncthreads();
    if (hA) {
#pragma unroll
        for (int k = 0; k < 4; k++) {
            int b = dA[k] >> 6;
            elist[sm[b] + pA[k]] = ((dA[k] & 63) << 16) | sA[k];
        }
    }
    if (hB) {
#pragma unroll
        for (int k = 0; k < 4; k++) {
            int b = dB[k] >> 6;
            elist[sm[b] + pB[k]] = ((dB[k] & 63) << 16) | sB[k];
        }
    }
    __syncthreads();
    int* gOut = gData + (size_t)(t * WPT + w) * CHE;
    for (int i = tid * 4; i < total; i += 2048)
        *(int4*)(gOut + i) = *(const int4*)&elist[i];
}

// ---- fused bucket-sum + exclusive scan per timestep ----
__global__ __launch_bounds__(512) void k_bscan2(const int* __restrict__ pcnt,
                                                int* __restrict__ bbase,
                                                int* __restrict__ rowptr) {
    int t = blockIdx.x, tid = threadIdx.x;
    __shared__ int sm[512];
    int v = 0;
    if (tid < NB)
        for (int w = 0; w < WPT; w++) v += pcnt[(size_t)(t * WPT + w) * NB + tid];
    sm[tid] = v;
    __syncthreads();
    for (int off = 1; off < 512; off <<= 1) {
        int u = (tid >= off) ? sm[tid - off] : 0;
        __syncthreads();
        sm[tid] += u;
        __syncthreads();
    }
    if (tid < NB) bbase[t * NB + tid] = sm[tid] - v;
    if (tid == 511) rowptr[(size_t)t * (NN + 1) + NN] = sm[511];
}

__global__ __launch_bounds__(256) void k_placeB(const int* __restrict__ gData,
                                                const int* __restrict__ pcnt,
                                                const int* __restrict__ pofs,
                                                const int* __restrict__ bbase,
                                                int* __restrict__ rowptr,
                                                float* __restrict__ dinv,
                                                unsigned short* __restrict__ csr) {
    int t = blockIdx.x / NB, b = blockIdx.x - t * NB;
    int tid = threadIdx.x;
    __shared__ int scnt[WPT], sofs[WPT], cofs[WPT + 1];
    __shared__ int elist[2048];
    __shared__ int cnt64[64], lofs[64], place[64];
    if (tid < WPT) {
        size_t o = (size_t)(t * WPT + tid) * NB + b;
        scnt[tid] = pcnt[o];
        sofs[tid] = pofs[o];
    }
    if (tid < 64) cnt64[tid] = 0;
    __syncthreads();
    if (tid == 0) {
        int s = 0;
        for (int w = 0; w < WPT; w++) { cofs[w] = s; s += scnt[w]; }
        cofs[WPT] = s;
    }
    __syncthreads();
    int total = cofs[WPT];
    int wv = tid >> 6, lane = tid & 63;
    for (int w = wv; w < WPT; w += 4) {
        int c = scnt[w], o = cofs[w];
        const int* sp = gData + (size_t)(t * WPT + w) * CHE + sofs[w];
        for (int i = lane; i < c; i += 64) elist[o + i] = sp[i];
    }
    __syncthreads();
    for (int i = tid; i < total; i += 256) atomicAdd(&cnt64[elist[i] >> 16], 1);
    __syncthreads();
    if (tid == 0) {
        int s = 0;
        for (int j = 0; j < 64; j++) { lofs[j] = s; place[j] = s; s += cnt64[j]; }
    }
    __syncthreads();
    int base = bbase[t * NB + b];
    int n = b * 64 + tid;
    if (tid < 64 && n < NN) {
        rowptr[(size_t)t * (NN + 1) + n] = base + lofs[tid];
        dinv[(size_t)t * NN + n] = rsqrtf(1.0f + (float)cnt64[tid]);
    }
    unsigned short* cbase = csr + (size_t)t * EE + base;
    for (int i = tid; i < total; i += 256) {
        int en = elist[i];
        int r = atomicAdd(&place[en >> 16], 1);
        cbase[r] = (unsigned short)(en & 0xffff);
    }
}

// ---------------- fallback CSR build (small ws_size) ----------------
__global__ void k_count(const int* __restrict__ ei, int* __restrict__ cnt) {
    int idx = blockIdx.x * 256 + threadIdx.x;
    if (idx >= TT * EE) return;
    int t = idx / EE, e = idx - t * EE;
    int d = ei[t * 2 * EE + EE + e];
    atomicAdd(&cnt[t * NN + d], 1);
}

__global__ void k_dinvF(const int* __restrict__ cnt, float* __restrict__ dinv) {
    int idx = blockIdx.x * 256 + threadIdx.x;
    if (idx >= TT * NN) return;
    dinv[idx] = 1.0f / sqrtf(1.0f + (float)cnt[idx]);
}

__global__ void k_scan(const int* __restrict__ cnt, int* __restrict__ rowptr, int* __restrict__ wofs) {
    int t = blockIdx.x;
    const int* c = cnt + t * NN;
    int* rp = rowptr + t * (NN + 1);
    int* wo = wofs + t * NN;
    __shared__ int sums[1024];
    int tid = threadIdx.x;
    const int CH2 = 20;
    int base = tid * CH2;
    int loc[CH2];
    int s = 0;
    for (int i = 0; i < CH2; i++) { int ix = base + i; int v = (ix < NN) ? c[ix] : 0; loc[i] = s; s += v; }
    sums[tid] = s;
    __syncthreads();
    for (int off = 1; off < 1024; off <<= 1) {
        int v = (tid >= off) ? sums[tid - off] : 0;
        __syncthreads();
        sums[tid] += v;
        __syncthreads();
    }
    int excl = (tid > 0) ? sums[tid - 1] : 0;
    for (int i = 0; i < CH2; i++) {
        int ix = base + i;
        if (ix < NN) { int e = excl + loc[i]; rp[ix] = e; wo[ix] = e; }
    }
    if (tid == 1023) rp[NN] = sums[1023];
}

__global__ void k_place(const int* __restrict__ ei, int* __restrict__ wofs,
                        unsigned short* __restrict__ csr) {
    int idx = blockIdx.x * 256 + threadIdx.x;
    if (idx >= TT * EE) return;
    int t = idx / EE, e = idx - t * EE;
    int s = ei[t * 2 * EE + e];
    int d = ei[t * 2 * EE + EE + e];
    int pos = atomicAdd(&wofs[t * NN + d], 1);
    csr[t * EE + pos] = (unsigned short)s;
}

// ---------------- fused TCN+proj weight prep (+ bias block) ----------------
// Bf32[384][128]: rows 0-127 = M2 (coeff of h_{t-2}), 128-255 = M1 (h_{t-1}),
// 256-383 = Mh (hg_t). Bpk = MFMA-packed single-step B for the decoder.
__global__ void k_wprepB(const float* __restrict__ cw, const float* __restrict__ pw,
                         const float* __restrict__ cb, const float* __restrict__ pb,
                         unsigned short* __restrict__ Bpk, float* __restrict__ Bf32,
                         float* __restrict__ bias) {
    int idx = blockIdx.x * 256 + threadIdx.x;
    if (blockIdx.x == 192) {
        int h = threadIdx.x;
        if (h < HH) {
            float m = pb[h];
            for (int d = 0; d < 3; d++)
                for (int o = 0; o < HH; o++)
                    m += cb[d * HH + o] * pw[h * 384 + d * HH + o];
            bias[h] = m;
        }
        return;
    }
    if (idx >= 384 * HH) return;
    int kk = idx / HH, h = idx - kk * HH;
    float m = 0.f;
    if (kk < 128) {
        int i = kk;
        for (int o = 0; o < HH; o++)
            m += cw[((1 * HH + o) * HH + i) * 3 + 0] * pw[h * 384 + 128 + o];
    } else if (kk < 256) {
        int i = kk - 128;
        for (int o = 0; o < HH; o++)
            m += cw[((0 * HH + o) * HH + i) * 3 + 0] * pw[h * 384 + o];
    } else {
        int i = kk - 256;
        for (int d = 0; d < 3; d++)
            for (int o = 0; o < HH; o++)
                m += cw[((d * HH + o) * HH + i) * 3 + 1] * pw[h * 384 + d * HH + o];
    }
    Bf32[kk * HH + h] = m;
    int ki = kk >> 5, r = kk & 31, q = r >> 3, j = r & 7, nt = h >> 4, ln = q * 16 + (h & 15);
    Bpk[(size_t)((ki * 8 + nt) * 64 + ln) * 8 + j] = f2b(m);
}

// ---------------- encoder collapse: T-chain weight build ----------------
// h_t = h_{t-2}M2 + h_{t-1}M1 + hg_t Mh + b  (linear in hg_s). Decoder needs
// only h_10, h_11:  h_10 = sum_s hg_s T_{10-s} + P_10 ; h_11 analogous.
// T_0 = Mh, T_j = T_{j-1}M1 + T_{j-2}M2 ; P_0 = b, P_j = P_{j-1}M1 + P_{j-2}M2 + b.
__global__ __launch_bounds__(128) void k_tchain(const float* __restrict__ Bf32,
                                                const float* __restrict__ biasT,
                                                unsigned short* __restrict__ Bq,
                                                float* __restrict__ biasQ) {
    __shared__ float v1[128], v2[128];
    int c = threadIdx.x;
    int r = blockIdx.x;
    const float* M2 = Bf32;
    const float* M1 = Bf32 + 128 * HH;
    const float* Mh = Bf32 + 256 * HH;
    if (r < 128) {
        int q4 = (r & 31) >> 3, jj = r & 7, rb = r >> 5;
        v1[c] = Mh[r * HH + c];     // T_0 row r
        v2[c] = 0.f;                // T_{-1}
        __syncthreads();
        // write T_0: half0 at s=10, half1 at s=11
        {
            float val = v1[c];
            int kb0 = 10 * 4 + rb, nt0 = c >> 4, ln = q4 * 16 + (c & 15);
            Bq[((size_t)(kb0 * 16 + nt0) * 64 + ln) * 8 + jj] = f2b(val);
            int kb1 = 11 * 4 + rb, nt1 = 8 + (c >> 4);
            Bq[((size_t)(kb1 * 16 + nt1) * 64 + ln) * 8 + jj] = f2b(val);
        }
        for (int j = 1; j < 12; j++) {
            float acc = 0.f;
            for (int k = 0; k < 128; k++)
                acc += v1[k] * M1[k * HH + c] + v2[k] * M2[k * HH + c];
            __syncthreads();
            v2[c] = v1[c]; v1[c] = acc;
            __syncthreads();
            int ln = q4 * 16 + (c & 15);
            if (j <= 10) {      // half0 (h_10): s = 10-j
                int kb = (10 - j) * 4 + rb, nt = c >> 4;
                Bq[((size_t)(kb * 16 + nt) * 64 + ln) * 8 + jj] = f2b(acc);
            }
            {                   // half1 (h_11): s = 11-j
                int kb = (11 - j) * 4 + rb, nt = 8 + (c >> 4);
                Bq[((size_t)(kb * 16 + nt) * 64 + ln) * 8 + jj] = f2b(acc);
            }
        }
        // zero-fill half0 of slice s=11 (h_10 has no hg_11 term)
        {
            int kb = 11 * 4 + rb, nt = c >> 4, ln = q4 * 16 + (c & 15);
            Bq[((size_t)(kb * 16 + nt) * 64 + ln) * 8 + jj] = 0;
        }
    } else {
        // bias chain: after loop v2 = P_10, v1 = P_11
        v1[c] = biasT[c];
        v2[c] = 0.f;
        __syncthreads();
        for (int j = 1; j < 12; j++) {
            float acc = biasT[c];
            for (int k = 0; k < 128; k++)
                acc += v1[k] * M1[k * HH + c] + v2[k] * M2[k * HH + c];
            __syncthreads();
            v2[c] = v1[c]; v1[c] = acc;
            __syncthreads();
        }
        biasQ[c] = v2[c];
        biasQ[128 + c] = v1[c];
    }
}

// ---------------- encoder front-end ----------------
__global__ void k_xs(const float* __restrict__ x, const float* __restrict__ dinv,
                     unsigned short* __restrict__ xs) {
    int idx = blockIdx.x * 256 + threadIdx.x;
    if (idx >= TT * NN) return;
    float dn = dinv[idx];
    const float4* xr = (const float4*)(x + (size_t)idx * FF);
    unsigned int res[8];
#pragma unroll
    for (int k = 0; k < 4; k++) {
        float4 v = xr[k];
        res[2 * k]     = pck(v.x * dn, v.y * dn);
        res[2 * k + 1] = pck(v.z * dn, v.w * dn);
    }
    uint4* dst = (uint4*)(xs + (size_t)idx * FF);
    dst[0] = *(uint4*)(res);
    dst[1] = *(uint4*)(res + 4);
}

// XCD-affinity aggregation (kept from R7: -20us vs round-robin).
__global__ __launch_bounds__(256) void k_aggX(const unsigned short* __restrict__ xsA,
                                              const unsigned short* __restrict__ csrA,
                                              const int* __restrict__ rpA,
                                              const float* __restrict__ dinvA,
                                              float* __restrict__ zA) {
    int bid = blockIdx.x;
    int x = bid & 7, k = bid >> 3;           // target XCD, slot 0..236
    int h = 3 * x + k / 79;                  // half-timestep 0..23
    int g = h >> 1;                          // timestep
    int nb = (h & 1) * 79 + (k % 79);        // 128-row block within timestep
    int tid = threadIdx.x;
    int r = tid >> 1, eo = tid & 1;          // 2 threads per row
    int n = nb * 128 + r;
    if (n >= NN) return;
    const unsigned short* xs = xsA + (size_t)g * NN * FF;
    const unsigned short* csr = csrA + (size_t)g * EE;
    const int* rp = rpA + (size_t)g * (NN + 1);
    float acc[16];
#pragma unroll
    for (int i = 0; i < 16; i++) acc[i] = 0.f;
    int j0 = rp[n], j1 = rp[n + 1];
    int j = j0 + eo;
    for (; j + 2 < j1; j += 4) {
        int s0 = csr[j], s1 = csr[j + 2];
        const uint4* p0 = (const uint4*)(xs + (size_t)s0 * FF);
        const uint4* p1 = (const uint4*)(xs + (size_t)s1 * FF);
        uint4 a0 = p0[0], a1 = p0[1], b0 = p1[0], b1 = p1[1];
        addrow(acc, a0); addrow(acc + 8, a1);
        addrow(acc, b0); addrow(acc + 8, b1);
    }
    if (j < j1) {
        const uint4* p0 = (const uint4*)(xs + (size_t)csr[j] * FF);
        uint4 a0 = p0[0], a1 = p0[1];
        addrow(acc, a0); addrow(acc + 8, a1);
    }
#pragma unroll
    for (int i = 0; i < 16; i++) acc[i] += __shfl_xor(acc[i], 1);
    if (eo == 0) {
        const uint4* sp = (const uint4*)(xs + (size_t)n * FF);
        uint4 a = sp[0], b4 = sp[1];
        addrow(acc, a); addrow(acc + 8, b4);
        float dn = dinvA[(size_t)g * NN + n];
        float4* zo = (float4*)(zA + (size_t)g * NP * FF + (size_t)n * FF);
#pragma unroll
        for (int k2 = 0; k2 < 4; k2++)
            zo[k2] = make_float4(acc[4 * k2] * dn, acc[4 * k2 + 1] * dn,
                                 acc[4 * k2 + 2] * dn, acc[4 * k2 + 3] * dn);
    }
}

// ---------------- ONE fused encoder gemm: [h10|h11] = sum_s relu(z_s Wg+gb) * T + P ----------------
// R10 (R9 counters: 9.1M LDS bank conflicts, 24 serial barriers):
// 1) producer remap hrow=tid&31, hc0=(tid>>5)*8 -> Wg reads are 2-address
//    broadcasts per wave (was 16 distinct addrs on even bank-quads = 2x serial).
// 2) double-buffered hgs + ONE barrier per slice: produce(s+1) overlaps MFMA(s)
//    (VALU and MFMA are separate pipes, m114). csh aliases hgs (dead after loop).
__global__ __launch_bounds__(512) void k_gemmE(const float* __restrict__ z12,
                                               const float* __restrict__ gw,
                                               const float* __restrict__ gb,
                                               const unsigned short* __restrict__ Bq,
                                               const float* __restrict__ biasQ,
                                               unsigned short* __restrict__ out0,
                                               unsigned short* __restrict__ out1) {
    __shared__ float Wg[FF * HH];
    __shared__ float gbs[HH];
    __shared__ float bqs[256];
    __shared__ __align__(16) unsigned short hgs[2][32 * 136];
    unsigned short* csh = &hgs[0][0];           // 32*264 shorts, alias (post-loop)
    int tid = threadIdx.x;
    int wid = tid >> 6, lane = tid & 63;
    int rg = wid & 1, cg = wid >> 1;
    int m0b = blockIdx.x * 32;
    int mr = lane & 15, q = lane >> 4;
    for (int i = tid; i < FF * HH; i += 512) Wg[i] = gw[i];
    if (tid < HH) gbs[tid] = gb[tid];
    if (tid >= 256 && tid < 512) bqs[tid - 256] = biasQ[tid - 256];
    __syncthreads();
    int nt0 = cg * 4;
    int hrow = tid & 31, hc0 = (tid >> 5) * 8;  // broadcast-friendly producer role
    auto produce = [&](int s, int buf) {
        const float4* zp = (const float4*)(z12 + ((size_t)s * NP + m0b + hrow) * FF);
        float4 z0 = zp[0], z1 = zp[1], z2 = zp[2], z3 = zp[3];
        float zr[16] = {z0.x, z0.y, z0.z, z0.w, z1.x, z1.y, z1.z, z1.w,
                        z2.x, z2.y, z2.z, z2.w, z3.x, z3.y, z3.z, z3.w};
        float sv[8];
#pragma unroll
        for (int c = 0; c < 8; c++) sv[c] = gbs[hc0 + c];
#pragma unroll
        for (int f = 0; f < 16; f++) {
            const float4* wp = (const float4*)(Wg + f * HH + hc0);
            float4 w0 = wp[0], w1 = wp[1];
            float zf = zr[f];
            sv[0] += zf * w0.x; sv[1] += zf * w0.y; sv[2] += zf * w0.z; sv[3] += zf * w0.w;
            sv[4] += zf * w1.x; sv[5] += zf * w1.y; sv[6] += zf * w1.z; sv[7] += zf * w1.w;
        }
        unsigned int res[4];
#pragma unroll
        for (int k = 0; k < 4; k++)
            res[k] = pck(fmaxf(sv[2 * k], 0.f), fmaxf(sv[2 * k + 1], 0.f));
        *(uint4*)&hgs[buf][hrow * 136 + hc0] = *(uint4*)res;
    };
    f32x4 acc[4];
#pragma unroll
    for (int j = 0; j < 4; j++) acc[j] = (f32x4){0.f, 0.f, 0.f, 0.f};
    produce(0, 0);
    __syncthreads();
    for (int s = 0; s < 12; s++) {
        int buf = s & 1;
        if (s < 11) produce(s + 1, buf ^ 1);    // overlaps with MFMA below
#pragma unroll
        for (int k2 = 0; k2 < 4; k2++) {
            int kb = s * 4 + k2;
            short8 bf[4];
#pragma unroll
            for (int j = 0; j < 4; j++)
                bf[j] = *(const short8*)(Bq + ((size_t)(kb * 16 + nt0 + j) * 64 + lane) * 8);
            short8 af = *(const short8*)&hgs[buf][(rg * 16 + mr) * 136 + k2 * 32 + q * 8];
#pragma unroll
            for (int j = 0; j < 4; j++)
                acc[j] = __builtin_amdgcn_mfma_f32_16x16x32_bf16(af, bf[j], acc[j], 0, 0, 0);
        }
        __syncthreads();    // produce(s+1) done AND hgs[buf] reads done
    }
#pragma unroll
    for (int j = 0; j < 4; j++) {
        int c = (nt0 + j) * 16 + mr;
        float bv = bqs[c];
#pragma unroll
        for (int r = 0; r < 4; r++)
            csh[(rg * 16 + q * 4 + r) * 264 + c] = f2b(acc[j][r] + bv);
    }
    __syncthreads();
#pragma unroll
    for (int i = 0; i < 2; i++) {
        int idx = i * 512 + tid;        // 0..1023: 32 rows x 32 chunks
        int row = idx >> 5, c8 = (idx & 31) * 8;
        short8 v = *(const short8*)&csh[row * 264 + c8];
        if (c8 < 128) *(short8*)(out0 + (size_t)(m0b + row) * HH + c8) = v;
        else          *(short8*)(out1 + (size_t)(m0b + row) * HH + (c8 - 128)) = v;
    }
}

// hg A-fragment (decoder): lane computes 32 hg values for row mr of a 16-row block
__device__ __forceinline__ void hg_frag(const float* zsh, const float* Wg, const float* gbs,
                                        int mr, int q, short8* hgf) {
    float zr[16];
    {
        const float4* zp = (const float4*)(zsh + mr * FF);
        float4 z0 = zp[0], z1 = zp[1], z2 = zp[2], z3 = zp[3];
        zr[0] = z0.x; zr[1] = z0.y; zr[2] = z0.z; zr[3] = z0.w;
        zr[4] = z1.x; zr[5] = z1.y; zr[6] = z1.z; zr[7] = z1.w;
        zr[8] = z2.x; zr[9] = z2.y; zr[10] = z2.z; zr[11] = z2.w;
        zr[12] = z3.x; zr[13] = z3.y; zr[14] = z3.z; zr[15] = z3.w;
    }
#pragma unroll
    for (int k2 = 0; k2 < 4; k2++) {
        float s[8];
#pragma unroll
        for (int c = 0; c < 8; c++) s[c] = gbs[k2 * 32 + q * 8 + c];
#pragma unroll
        for (int f = 0; f < 16; f++) {
            const float4* wp = (const float4*)(Wg + f * HH + k2 * 32 + q * 8);
            float4 w0 = wp[0], w1 = wp[1];
            float zf = zr[f];
            s[0] += zf * w0.x; s[1] += zf * w0.y; s[2] += zf * w0.z; s[3] += zf * w0.w;
            s[4] += zf * w1.x; s[5] += zf * w1.y; s[6] += zf * w1.z; s[7] += zf * w1.w;
        }
#pragma unroll
        for (int c = 0; c < 8; c++) hgf[k2][c] = (short)f2b(fmaxf(s[c], 0.f));
    }
}

// ---------------- decoder fused step: [gather] + gemm + head + feedback ----------------
// 16-row blocks, 4 waves x (16 rows x 32 cols). (unchanged from R6/R7)
__global__ __launch_bounds__(256, 3) void k_gemmF2(const unsigned short* __restrict__ a0,
                                                   const unsigned short* __restrict__ a1,
                                                   const float* __restrict__ zt, int gather,
                                                   const float* __restrict__ gw,
                                                   const float* __restrict__ gb,
                                                   const unsigned short* __restrict__ Bpk,
                                                   const float* __restrict__ bias,
                                                   unsigned short* __restrict__ out,
                                                   const float* __restrict__ hw,
                                                   const float* __restrict__ hbv,
                                                   const float* __restrict__ dinvN,
                                                   const int* __restrict__ rp,
                                                   const unsigned short* __restrict__ csr,
                                                   unsigned short* __restrict__ xsD,
                                                   float* __restrict__ yout) {
    __shared__ float Wg[FF * HH];
    __shared__ float Whs[CC * 132];     // padded: kills 16-way head bank conflict
    __shared__ float gbs[HH], biasS[HH], hbS[CC];
    __shared__ float zsh[16 * FF];
    __shared__ __align__(16) unsigned short hgD[16 * 136];
    __shared__ unsigned short hsh[16 * 136];
    __shared__ float ysh[16 * 17];
    int tid = threadIdx.x;
    int wid = tid >> 6, lane = tid & 63;
    int m0b = blockIdx.x * 16;
    int mr = lane & 15, q = lane >> 4;
    for (int i = tid; i < FF * HH; i += 256) {
        Wg[i] = gw[i];
        Whs[(i >> 7) * 132 + (i & 127)] = hw[i];
    }
    if (tid < HH) { gbs[tid] = gb[tid]; biasS[tid] = bias[tid]; }
    if (tid < CC) hbS[tid] = hbv[tid];
    if (!gather) {
        if (tid < 16 * FF) zsh[tid] = zt[(size_t)m0b * FF + tid];
    } else {
        // in-tile 16-dim aggregation from xsD: 16 threads/row (2 halves x 8-way edges)
        int r = tid >> 4, p = tid & 15, half = p & 1, eo = p >> 1;
        int n = m0b + r;
        float a[8];
#pragma unroll
        for (int k = 0; k < 8; k++) a[k] = 0.f;
        if (n < NN) {
            int j0 = rp[n], j1 = rp[n + 1];
            for (int j = j0 + eo; j < j1; j += 8) {
                int s = csr[j];
                uint4 v = *(const uint4*)(xsD + (size_t)s * FF + half * 8);
                addrow(a, v);
            }
        }
#pragma unroll
        for (int k = 0; k < 8; k++) {
            a[k] += __shfl_xor(a[k], 2);
            a[k] += __shfl_xor(a[k], 4);
            a[k] += __shfl_xor(a[k], 8);
        }
        if (n < NN && eo == 0) {
            uint4 sv = *(const uint4*)(xsD + (size_t)n * FF + half * 8);
            addrow(a, sv);
            float dn = dinvN[n];
#pragma unroll
            for (int k = 0; k < 8; k++) zsh[r * FF + half * 8 + k] = a[k] * dn;
        }
    }
    __syncthreads();
    if (wid == 0) {
        short8 hgf[4];
        hg_frag(zsh, Wg, gbs, mr, q, hgf);
#pragma unroll
        for (int k2 = 0; k2 < 4; k2++)
            *(short8*)&hgD[mr * 136 + k2 * 32 + q * 8] = hgf[k2];
    }
    __syncthreads();
    int nt0 = wid * 2;                  // wave's 2 col tiles (32 cols)
    f32x4 acc[2];
#pragma unroll
    for (int j = 0; j < 2; j++) acc[j] = (f32x4){0.f, 0.f, 0.f, 0.f};
#pragma unroll
    for (int ki = 0; ki < 12; ki++) {
        short8 bf[2];
#pragma unroll
        for (int j = 0; j < 2; j++)
            bf[j] = *(const short8*)(Bpk + (size_t)((ki * 8 + nt0 + j) * 64 + lane) * 8);
        short8 af;
        if (ki < 4)
            af = *(const short8*)(a0 + (size_t)(m0b + mr) * HH + ki * 32 + q * 8);
        else if (ki < 8)
            af = *(const short8*)(a1 + (size_t)(m0b + mr) * HH + (ki - 4) * 32 + q * 8);
        else
            af = *(const short8*)&hgD[mr * 136 + (ki - 8) * 32 + q * 8];
#pragma unroll
        for (int j = 0; j < 2; j++)
            acc[j] = __builtin_amdgcn_mfma_f32_16x16x32_bf16(af, bf[j], acc[j], 0, 0, 0);
    }
#pragma unroll
    for (int j = 0; j < 2; j++) {
        int feat = (nt0 + j) * 16 + mr;
        float bv = biasS[feat];
#pragma unroll
        for (int r = 0; r < 4; r++)
            hsh[(q * 4 + r) * 136 + feat] = f2b(acc[j][r] + bv);
    }
    __syncthreads();
    // coalesced h write-out (16B/lane): 16 rows x 16 chunks = 256
    {
        int row = tid >> 4, c8 = (tid & 15) * 8;
        *(short8*)(out + (size_t)(m0b + row) * HH + c8) =
            *(const short8*)&hsh[row * 136 + c8];
    }
    // head: y[n][c] = hb[c] + sum_k h[n][k]*Wh[c][k]; 1 thread per (row, col)
    {
        int r = tid >> 4, c = tid & 15;
        float y = hbS[c];
        for (int k = 0; k < HH; k++)
            y += blo((unsigned int)hsh[r * 136 + k]) * Whs[c * 132 + k];
        ysh[r * 17 + c] = y;
        int gn = m0b + r;
        if (gn < NN) yout[(size_t)gn * CC + c] = y;
    }
    __syncthreads();
    // next-step xs: xsD[n][k] = bf16(y[n][k] * dinv[n])
    if (tid < 16) {
        int gn = m0b + tid;
        if (gn < NN) {
            float dn = dinvN[gn];
            unsigned int res[8];
#pragma unroll
            for (int k = 0; k < 8; k++)
                res[k] = pck(ysh[tid * 17 + 2 * k] * dn, ysh[tid * 17 + 2 * k + 1] * dn);
            uint4* dst = (uint4*)(xsD + (size_t)gn * FF);
            dst[0] = *(uint4*)(res);
            dst[1] = *(uint4*)(res + 4);
        }
    }
}

extern "C" void kernel_launch(void* const* d_in, const int* in_sizes, int n_in,
                              void* d_out, int out_size, void* d_ws, size_t ws_size,
                              hipStream_t stream) {
    const float* x_seq  = (const float*)d_in[0];
    const int*   ei     = (const int*)d_in[1];
    const float* gcn_w  = (const float*)d_in[5];
    const float* gcn_b  = (const float*)d_in[6];
    const float* conv_w = (const float*)d_in[7];
    const float* conv_b = (const float*)d_in[8];
    const float* proj_w = (const float*)d_in[9];
    const float* proj_b = (const float*)d_in[10];
    const float* head_w = (const float*)d_in[11];
    const float* head_b = (const float*)d_in[12];
    float* outp = (float*)d_out;

    char* ws = (char*)d_ws;
    size_t off = 0;
    auto alloc = [&](size_t bytes) { void* p = ws + off; off += (bytes + 255) & ~(size_t)255; return p; };
    // persistent
    float*          dinv   = (float*)alloc((size_t)TT * NN * 4);
    int*            rowptr = (int*)alloc((size_t)TT * (NN + 1) * 4);
    unsigned short* csr    = (unsigned short*)alloc((size_t)TT * EE * 2);
    unsigned short* hb0    = (unsigned short*)alloc((size_t)NP * HH * 2);
    unsigned short* hb1    = (unsigned short*)alloc((size_t)NP * HH * 2);
    unsigned short* hb2    = (unsigned short*)alloc((size_t)NP * HH * 2);
    unsigned short* hb3    = (unsigned short*)alloc((size_t)NP * HH * 2);
    unsigned short* xsD    = (unsigned short*)alloc((size_t)NP * FF * 2);
    unsigned short* Bpk    = (unsigned short*)alloc((size_t)384 * HH * 2);
    float*          Bf32   = (float*)alloc((size_t)384 * HH * 4);
    float*          biasT  = (float*)alloc(HH * 4);
    // transient B: encoder xs + z + Bq
    size_t tb = off;
    unsigned short* xs12  = (unsigned short*)alloc((size_t)TT * NN * FF * 2);
    float*          z12   = (float*)alloc((size_t)TT * NP * FF * 4);
    unsigned short* Bq    = (unsigned short*)alloc((size_t)48 * 16 * 64 * 8 * 2);
    float*          biasQ = (float*)alloc(256 * 4);
    size_t compute_end = off;
    // transient A: CSR-build scratch, aliased over transient B
    off = tb;
    int* gData = (int*)alloc((size_t)TT * WPT * CHE * 4);
    int* pcnt  = (int*)alloc((size_t)TT * WPT * NB * 4);
    int* pofs  = (int*)alloc((size_t)TT * WPT * NB * 4);
    int* bbase = (int*)alloc((size_t)TT * NB * 4);
    size_t csr_end = off;
    bool fastcsr = (csr_end <= ws_size && compute_end <= ws_size);

    if (fastcsr) {
        k_binA<<<TT * WPT, 512, 0, stream>>>(ei, gData, pcnt, pofs);
        k_bscan2<<<TT, 512, 0, stream>>>(pcnt, bbase, rowptr);
        k_placeB<<<TT * NB, 256, 0, stream>>>(gData, pcnt, pofs, bbase, rowptr, dinv, csr);
    } else {
        off = tb;
        int* cnt  = (int*)alloc((size_t)TT * NN * 4);
        int* wofs = (int*)alloc((size_t)TT * NN * 4);
        k_zero<<<(TT * NN + 255) / 256, 256, 0, stream>>>(cnt, TT * NN);
        k_count<<<(TT * EE + 255) / 256, 256, 0, stream>>>(ei, cnt);
        k_dinvF<<<(TT * NN + 255) / 256, 256, 0, stream>>>(cnt, dinv);
        k_scan<<<TT, 1024, 0, stream>>>(cnt, rowptr, wofs);
        k_place<<<(TT * EE + 255) / 256, 256, 0, stream>>>(ei, wofs, csr);
    }

    k_wprepB<<<193, 256, 0, stream>>>(conv_w, proj_w, conv_b, proj_b, Bpk, Bf32, biasT);
    k_tchain<<<129, 128, 0, stream>>>(Bf32, biasT, Bq, biasQ);

    // encoder front-end: xs, aggregation, then ONE fused hg+composed gemm
    k_xs<<<(TT * NN + 255) / 256, 256, 0, stream>>>(x_seq, dinv, xs12);
    k_aggX<<<AGG_GRID, 256, 0, stream>>>(xs12, csr, rowptr, dinv, z12);
    k_gemmE<<<NP / 32, 512, 0, stream>>>(z12, gcn_w, gcn_b, Bq, biasQ, hb2, hb3);   // h10 -> hb2, h11 -> hb3

    // decoder: t=12 reuses z(t=11); later steps gather in-tile from xsD
    unsigned short* hbuf[4] = {hb0, hb1, hb2, hb3};
    const float* dinv11 = dinv + (size_t)(TT - 1) * NN;
    const int* rp11 = rowptr + (size_t)(TT - 1) * (NN + 1);
    const unsigned short* csr11 = csr + (size_t)(TT - 1) * EE;
    for (int t = TT; t < TT + HOR; t++) {
        const float* zt = (t == TT) ? (z12 + (size_t)(TT - 1) * NP * FF) : nullptr;
        k_gemmF2<<<NP / 16, 256, 0, stream>>>(hbuf[(t + 2) & 3], hbuf[(t + 3) & 3],
                                              zt, (t == TT) ? 0 : 1,
                                              gcn_w, gcn_b, Bpk, biasT, hbuf[t & 3],
                                              head_w, head_b, dinv11, rp11, csr11,
                                              xsD, outp + (size_t)(t - TT) * NN * CC);
    }
}

// Round 11
// 428.235 us; speedup vs baseline: 1.1647x; 1.0197x over previous
//
#include <hip/hip_runtime.h>

#define NN 20000
#define NP 20032   // padded rows
#define EE 320000
#define TT 12
#define HH 128
#define FF 16
#define CC 16
#define HOR 6

// binning-sort parameters (CSR build)
#define NB 313      // buckets of 64 dst nodes
#define WPT 84      // binning workgroups per timestep
#define CHE 3812    // edges per binning WG (ceil(EE/WPT) rounded to mult of 4)

#define AGG_GRID 1896   // 8 XCDs x 3 half-timesteps x 79 blocks

typedef __attribute__((ext_vector_type(8))) short short8;
typedef __attribute__((ext_vector_type(4))) float f32x4;

__device__ __forceinline__ float blo(unsigned int u) {
    union { float f; unsigned int i; } v; v.i = u << 16; return v.f;
}
__device__ __forceinline__ float bhi(unsigned int u) {
    union { float f; unsigned int i; } v; v.i = u & 0xffff0000u; return v.f;
}
__device__ __forceinline__ unsigned short f2b(float f) {
    union { float f; unsigned int i; } v; v.f = f;
    unsigned int x = v.i;
    return (unsigned short)((x + 0x7fffu + ((x >> 16) & 1u)) >> 16);
}
__device__ __forceinline__ unsigned int pck(float lo, float hi) {
    return ((unsigned int)f2b(hi) << 16) | f2b(lo);
}
__device__ __forceinline__ void addrow(float* acc, uint4 r) {
    acc[0] += blo(r.x); acc[1] += bhi(r.x);
    acc[2] += blo(r.y); acc[3] += bhi(r.y);
    acc[4] += blo(r.z); acc[5] += bhi(r.z);
    acc[6] += blo(r.w); acc[7] += bhi(r.w);
}

// ---------------- setup kernels ----------------
__global__ void k_zero(int* p, int n) {
    int i = blockIdx.x * 256 + threadIdx.x;
    if (i < n) p[i] = 0;
}

// ---- CSR build phase A: LDS counting-sort of each WG's chunk, coalesced write-out ----
__global__ __launch_bounds__(512) void k_binA(const int* __restrict__ ei,
                                              int* __restrict__ gData,
                                              int* __restrict__ pcnt,
                                              int* __restrict__ pofs) {
    int wg = blockIdx.x;
    int t = wg / WPT, w = wg - t * WPT;
    __shared__ int lcnt[NB];
    __shared__ int sm[512];
    __shared__ __align__(16) int elist[CHE];
    int tid = threadIdx.x;
    for (int i = tid; i < NB; i += 512) lcnt[i] = 0;
    __syncthreads();
    int e0 = w * CHE, e1 = min(EE, e0 + CHE);
    int total = e1 - e0;                       // always a multiple of 4
    const int* si = ei + (size_t)t * 2 * EE;
    const int* di = si + EE;
    int eA = e0 + tid * 4, eB = eA + 2048;
    bool hA = eA < e1, hB = eB < e1;
    int sA[4], dA[4], pA[4], sB[4], dB[4], pB[4];
    if (hA) {
        int4 s4 = *(const int4*)(si + eA);
        int4 d4 = *(const int4*)(di + eA);
        sA[0] = s4.x; sA[1] = s4.y; sA[2] = s4.z; sA[3] = s4.w;
        dA[0] = d4.x; dA[1] = d4.y; dA[2] = d4.z; dA[3] = d4.w;
    }
    if (hB) {
        int4 s4 = *(const int4*)(si + eB);
        int4 d4 = *(const int4*)(di + eB);
        sB[0] = s4.x; sB[1] = s4.y; sB[2] = s4.z; sB[3] = s4.w;
        dB[0] = d4.x; dB[1] = d4.y; dB[2] = d4.z; dB[3] = d4.w;
    }
    if (hA) {
#pragma unroll
        for (int k = 0; k < 4; k++) pA[k] = atomicAdd(&lcnt[dA[k] >> 6], 1);
    }
    if (hB) {
#pragma unroll
        for (int k = 0; k < 4; k++) pB[k] = atomicAdd(&lcnt[dB[k] >> 6], 1);
    }
    __syncthreads();
    sm[tid] = (tid < NB) ? lcnt[tid] : 0;
    __syncthreads();
    for (int off = 1; off < 512; off <<= 1) {
        int u = (tid >= off) ? sm[tid - off] : 0;
        __syncthreads();
        sm[tid] += u;
        __syncthreads();
    }
    if (tid < NB) {
        int v = lcnt[tid];
        int ex = sm[tid] - v;
        size_t o = (size_t)(t * WPT + w) * NB + tid;
        pcnt[o] = v;
        pofs[o] = ex;
        sm[tid] = ex;      // sm now holds exclusive bucket offsets
    }
    __syncthreads();
    if (hA) {
#pragma unroll
        for (int k = 0; k < 4; k++) {
            int b = dA[k] >> 6;
            elist[sm[b] + pA[k]] = ((dA[k] & 63) << 16) | sA[k];
        }
    }
    if (hB) {
#pragma unroll
        for (int k = 0; k < 4; k++) {
            int b = dB[k] >> 6;
            elist[sm[b] + pB[k]] = ((dB[k] & 63) << 16) | sB[k];
        }
    }
    __syncthreads();
    int* gOut = gData + (size_t)(t * WPT + w) * CHE;
    for (int i = tid * 4; i < total; i += 2048)
        *(int4*)(gOut + i) = *(const int4*)&elist[i];
}

// ---- fused bucket-sum + exclusive scan per timestep ----
__global__ __launch_bounds__(512) void k_bscan2(const int* __restrict__ pcnt,
                                                int* __restrict__ bbase,
                                                int* __restrict__ rowptr) {
    int t = blockIdx.x, tid = threadIdx.x;
    __shared__ int sm[512];
    int v = 0;
    if (tid < NB)
        for (int w = 0; w < WPT; w++) v += pcnt[(size_t)(t * WPT + w) * NB + tid];
    sm[tid] = v;
    __syncthreads();
    for (int off = 1; off < 512; off <<= 1) {
        int u = (tid >= off) ? sm[tid - off] : 0;
        __syncthreads();
        sm[tid] += u;
        __syncthreads();
    }
    if (tid < NB) bbase[t * NB + tid] = sm[tid] - v;
    if (tid == 511) rowptr[(size_t)t * (NN + 1) + NN] = sm[511];
}

__global__ __launch_bounds__(256) void k_placeB(const int* __restrict__ gData,
                                                const int* __restrict__ pcnt,
                                                const int* __restrict__ pofs,
                                                const int* __restrict__ bbase,
                                                int* __restrict__ rowptr,
                                                float* __restrict__ dinv,
                                                unsigned short* __restrict__ csr) {
    int t = blockIdx.x / NB, b = blockIdx.x - t * NB;
    int tid = threadIdx.x;
    __shared__ int scnt[WPT], sofs[WPT], cofs[WPT + 1];
    __shared__ int elist[2048];
    __shared__ int cnt64[64], lofs[64], place[64];
    if (tid < WPT) {
        size_t o = (size_t)(t * WPT + tid) * NB + b;
        scnt[tid] = pcnt[o];
        sofs[tid] = pofs[o];
    }
    if (tid < 64) cnt64[tid] = 0;
    __syncthreads();
    if (tid == 0) {
        int s = 0;
        for (int w = 0; w < WPT; w++) { cofs[w] = s; s += scnt[w]; }
        cofs[WPT] = s;
    }
    __syncthreads();
    int total = cofs[WPT];
    int wv = tid >> 6, lane = tid & 63;
    for (int w = wv; w < WPT; w += 4) {
        int c = scnt[w], o = cofs[w];
        const int* sp = gData + (size_t)(t * WPT + w) * CHE + sofs[w];
        for (int i = lane; i < c; i += 64) elist[o + i] = sp[i];
    }
    __syncthreads();
    for (int i = tid; i < total; i += 256) atomicAdd(&cnt64[elist[i] >> 16], 1);
    __syncthreads();
    if (tid == 0) {
        int s = 0;
        for (int j = 0; j < 64; j++) { lofs[j] = s; place[j] = s; s += cnt64[j]; }
    }
    __syncthreads();
    int base = bbase[t * NB + b];
    int n = b * 64 + tid;
    if (tid < 64 && n < NN) {
        rowptr[(size_t)t * (NN + 1) + n] = base + lofs[tid];
        dinv[(size_t)t * NN + n] = rsqrtf(1.0f + (float)cnt64[tid]);
    }
    unsigned short* cbase = csr + (size_t)t * EE + base;
    for (int i = tid; i < total; i += 256) {
        int en = elist[i];
        int r = atomicAdd(&place[en >> 16], 1);
        cbase[r] = (unsigned short)(en & 0xffff);
    }
}

// ---------------- fallback CSR build (small ws_size) ----------------
__global__ void k_count(const int* __restrict__ ei, int* __restrict__ cnt) {
    int idx = blockIdx.x * 256 + threadIdx.x;
    if (idx >= TT * EE) return;
    int t = idx / EE, e = idx - t * EE;
    int d = ei[t * 2 * EE + EE + e];
    atomicAdd(&cnt[t * NN + d], 1);
}

__global__ void k_dinvF(const int* __restrict__ cnt, float* __restrict__ dinv) {
    int idx = blockIdx.x * 256 + threadIdx.x;
    if (idx >= TT * NN) return;
    dinv[idx] = 1.0f / sqrtf(1.0f + (float)cnt[idx]);
}

__global__ void k_scan(const int* __restrict__ cnt, int* __restrict__ rowptr, int* __restrict__ wofs) {
    int t = blockIdx.x;
    const int* c = cnt + t * NN;
    int* rp = rowptr + t * (NN + 1);
    int* wo = wofs + t * NN;
    __shared__ int sums[1024];
    int tid = threadIdx.x;
    const int CH2 = 20;
    int base = tid * CH2;
    int loc[CH2];
    int s = 0;
    for (int i = 0; i < CH2; i++) { int ix = base + i; int v = (ix < NN) ? c[ix] : 0; loc[i] = s; s += v; }
    sums[tid] = s;
    __syncthreads();
    for (int off = 1; off < 1024; off <<= 1) {
        int v = (tid >= off) ? sums[tid - off] : 0;
        __syncthreads();
        sums[tid] += v;
        __syncthreads();
    }
    int excl = (tid > 0) ? sums[tid - 1] : 0;
    for (int i = 0; i < CH2; i++) {
        int ix = base + i;
        if (ix < NN) { int e = excl + loc[i]; rp[ix] = e; wo[ix] = e; }
    }
    if (tid == 1023) rp[NN] = sums[1023];
}

__global__ void k_place(const int* __restrict__ ei, int* __restrict__ wofs,
                        unsigned short* __restrict__ csr) {
    int idx = blockIdx.x * 256 + threadIdx.x;
    if (idx >= TT * EE) return;
    int t = idx / EE, e = idx - t * EE;
    int s = ei[t * 2 * EE + e];
    int d = ei[t * 2 * EE + EE + e];
    int pos = atomicAdd(&wofs[t * NN + d], 1);
    csr[t * EE + pos] = (unsigned short)s;
}

// ---------------- fused TCN+proj weight prep (+ bias block) ----------------
// Bf32[384][128]: rows 0-127 = M2 (coeff of h_{t-2}), 128-255 = M1 (h_{t-1}),
// 256-383 = Mh (hg_t). Bpk = MFMA-packed single-step B for the decoder.
__global__ void k_wprepB(const float* __restrict__ cw, const float* __restrict__ pw,
                         const float* __restrict__ cb, const float* __restrict__ pb,
                         unsigned short* __restrict__ Bpk, float* __restrict__ Bf32,
                         float* __restrict__ bias) {
    int idx = blockIdx.x * 256 + threadIdx.x;
    if (blockIdx.x == 192) {
        int h = threadIdx.x;
        if (h < HH) {
            float m = pb[h];
            for (int d = 0; d < 3; d++)
                for (int o = 0; o < HH; o++)
                    m += cb[d * HH + o] * pw[h * 384 + d * HH + o];
            bias[h] = m;
        }
        return;
    }
    if (idx >= 384 * HH) return;
    int kk = idx / HH, h = idx - kk * HH;
    float m = 0.f;
    if (kk < 128) {
        int i = kk;
        for (int o = 0; o < HH; o++)
            m += cw[((1 * HH + o) * HH + i) * 3 + 0] * pw[h * 384 + 128 + o];
    } else if (kk < 256) {
        int i = kk - 128;
        for (int o = 0; o < HH; o++)
            m += cw[((0 * HH + o) * HH + i) * 3 + 0] * pw[h * 384 + o];
    } else {
        int i = kk - 256;
        for (int d = 0; d < 3; d++)
            for (int o = 0; o < HH; o++)
                m += cw[((d * HH + o) * HH + i) * 3 + 1] * pw[h * 384 + d * HH + o];
    }
    Bf32[kk * HH + h] = m;
    int ki = kk >> 5, r = kk & 31, q = r >> 3, j = r & 7, nt = h >> 4, ln = q * 16 + (h & 15);
    Bpk[(size_t)((ki * 8 + nt) * 64 + ln) * 8 + j] = f2b(m);
}

// ---------------- encoder collapse: T-chain weight build ----------------
// h_t = h_{t-2}M2 + h_{t-1}M1 + hg_t Mh + b  (linear in hg_s). Decoder needs
// only h_10, h_11:  h_10 = sum_s hg_s T_{10-s} + P_10 ; h_11 analogous.
// T_0 = Mh, T_j = T_{j-1}M1 + T_{j-2}M2 ; P_0 = b, P_j = P_{j-1}M1 + P_{j-2}M2 + b.
__global__ __launch_bounds__(128) void k_tchain(const float* __restrict__ Bf32,
                                                const float* __restrict__ biasT,
                                                unsigned short* __restrict__ Bq,
                                                float* __restrict__ biasQ) {
    __shared__ float v1[128], v2[128];
    int c = threadIdx.x;
    int r = blockIdx.x;
    const float* M2 = Bf32;
    const float* M1 = Bf32 + 128 * HH;
    const float* Mh = Bf32 + 256 * HH;
    if (r < 128) {
        int q4 = (r & 31) >> 3, jj = r & 7, rb = r >> 5;
        v1[c] = Mh[r * HH + c];     // T_0 row r
        v2[c] = 0.f;                // T_{-1}
        __syncthreads();
        // write T_0: half0 at s=10, half1 at s=11
        {
            float val = v1[c];
            int kb0 = 10 * 4 + rb, nt0 = c >> 4, ln = q4 * 16 + (c & 15);
            Bq[((size_t)(kb0 * 16 + nt0) * 64 + ln) * 8 + jj] = f2b(val);
            int kb1 = 11 * 4 + rb, nt1 = 8 + (c >> 4);
            Bq[((size_t)(kb1 * 16 + nt1) * 64 + ln) * 8 + jj] = f2b(val);
        }
        for (int j = 1; j < 12; j++) {
            float acc = 0.f;
            for (int k = 0; k < 128; k++)
                acc += v1[k] * M1[k * HH + c] + v2[k] * M2[k * HH + c];
            __syncthreads();
            v2[c] = v1[c]; v1[c] = acc;
            __syncthreads();
            int ln = q4 * 16 + (c & 15);
            if (j <= 10) {      // half0 (h_10): s = 10-j
                int kb = (10 - j) * 4 + rb, nt = c >> 4;
                Bq[((size_t)(kb * 16 + nt) * 64 + ln) * 8 + jj] = f2b(acc);
            }
            {                   // half1 (h_11): s = 11-j
                int kb = (11 - j) * 4 + rb, nt = 8 + (c >> 4);
                Bq[((size_t)(kb * 16 + nt) * 64 + ln) * 8 + jj] = f2b(acc);
            }
        }
        // zero-fill half0 of slice s=11 (h_10 has no hg_11 term)
        {
            int kb = 11 * 4 + rb, nt = c >> 4, ln = q4 * 16 + (c & 15);
            Bq[((size_t)(kb * 16 + nt) * 64 + ln) * 8 + jj] = 0;
        }
    } else {
        // bias chain: after loop v2 = P_10, v1 = P_11
        v1[c] = biasT[c];
        v2[c] = 0.f;
        __syncthreads();
        for (int j = 1; j < 12; j++) {
            float acc = biasT[c];
            for (int k = 0; k < 128; k++)
                acc += v1[k] * M1[k * HH + c] + v2[k] * M2[k * HH + c];
            __syncthreads();
            v2[c] = v1[c]; v1[c] = acc;
            __syncthreads();
        }
        biasQ[c] = v2[c];
        biasQ[128 + c] = v1[c];
    }
}

// ---------------- encoder front-end ----------------
__global__ void k_xs(const float* __restrict__ x, const float* __restrict__ dinv,
                     unsigned short* __restrict__ xs) {
    int idx = blockIdx.x * 256 + threadIdx.x;
    if (idx >= TT * NN) return;
    float dn = dinv[idx];
    const float4* xr = (const float4*)(x + (size_t)idx * FF);
    unsigned int res[8];
#pragma unroll
    for (int k = 0; k < 4; k++) {
        float4 v = xr[k];
        res[2 * k]     = pck(v.x * dn, v.y * dn);
        res[2 * k + 1] = pck(v.z * dn, v.w * dn);
    }
    uint4* dst = (uint4*)(xs + (size_t)idx * FF);
    dst[0] = *(uint4*)(res);
    dst[1] = *(uint4*)(res + 4);
}

// XCD-affinity aggregation (kept from R7: -20us vs round-robin).
__global__ __launch_bounds__(256) void k_aggX(const unsigned short* __restrict__ xsA,
                                              const unsigned short* __restrict__ csrA,
                                              const int* __restrict__ rpA,
                                              const float* __restrict__ dinvA,
                                              float* __restrict__ zA) {
    int bid = blockIdx.x;
    int x = bid & 7, k = bid >> 3;           // target XCD, slot 0..236
    int h = 3 * x + k / 79;                  // half-timestep 0..23
    int g = h >> 1;                          // timestep
    int nb = (h & 1) * 79 + (k % 79);        // 128-row block within timestep
    int tid = threadIdx.x;
    int r = tid >> 1, eo = tid & 1;          // 2 threads per row
    int n = nb * 128 + r;
    if (n >= NN) return;
    const unsigned short* xs = xsA + (size_t)g * NN * FF;
    const unsigned short* csr = csrA + (size_t)g * EE;
    const int* rp = rpA + (size_t)g * (NN + 1);
    float acc[16];
#pragma unroll
    for (int i = 0; i < 16; i++) acc[i] = 0.f;
    int j0 = rp[n], j1 = rp[n + 1];
    int j = j0 + eo;
    for (; j + 2 < j1; j += 4) {
        int s0 = csr[j], s1 = csr[j + 2];
        const uint4* p0 = (const uint4*)(xs + (size_t)s0 * FF);
        const uint4* p1 = (const uint4*)(xs + (size_t)s1 * FF);
        uint4 a0 = p0[0], a1 = p0[1], b0 = p1[0], b1 = p1[1];
        addrow(acc, a0); addrow(acc + 8, a1);
        addrow(acc, b0); addrow(acc + 8, b1);
    }
    if (j < j1) {
        const uint4* p0 = (const uint4*)(xs + (size_t)csr[j] * FF);
        uint4 a0 = p0[0], a1 = p0[1];
        addrow(acc, a0); addrow(acc + 8, a1);
    }
#pragma unroll
    for (int i = 0; i < 16; i++) acc[i] += __shfl_xor(acc[i], 1);
    if (eo == 0) {
        const uint4* sp = (const uint4*)(xs + (size_t)n * FF);
        uint4 a = sp[0], b4 = sp[1];
        addrow(acc, a); addrow(acc + 8, b4);
        float dn = dinvA[(size_t)g * NN + n];
        float4* zo = (float4*)(zA + (size_t)g * NP * FF + (size_t)n * FF);
#pragma unroll
        for (int k2 = 0; k2 < 4; k2++)
            zo[k2] = make_float4(acc[4 * k2] * dn, acc[4 * k2 + 1] * dn,
                                 acc[4 * k2 + 2] * dn, acc[4 * k2 + 3] * dn);
    }
}

// ---------------- ONE fused encoder gemm: [h10|h11] = sum_s relu(z_s Wg+gb) * T + P ----------------
// R11 (R10 counters: conflicts fixed but dur 84->80 only; Occ 27.8% = 1.1 resident
// block/CU, ~44us barrier/latency stall): apply the R5->R6 TLP medicine.
// 16-row tiles -> 1252 blocks x 256 thr (4 waves, wave = 4 col-tiles = 64 cols).
// Per-wave issue work unchanged; blocks/CU 2.45 -> 4.9, LDS 27KB -> 18KB so
// 4+ blocks co-reside and barrier stalls overlap across blocks.
__global__ __launch_bounds__(256, 4) void k_gemmE(const float* __restrict__ z12,
                                                  const float* __restrict__ gw,
                                                  const float* __restrict__ gb,
                                                  const unsigned short* __restrict__ Bq,
                                                  const float* __restrict__ biasQ,
                                                  unsigned short* __restrict__ out0,
                                                  unsigned short* __restrict__ out1) {
    __shared__ float Wg[FF * HH];
    __shared__ float gbs[HH];
    __shared__ float bqs[256];
    __shared__ __align__(16) unsigned short hgs[2][16 * 136];
    unsigned short* csh = &hgs[0][0];           // 16*264 shorts, alias (post-loop)
    int tid = threadIdx.x;
    int cg = tid >> 6, lane = tid & 63;
    int m0b = blockIdx.x * 16;
    int mr = lane & 15, q = lane >> 4;
    for (int i = tid; i < FF * HH; i += 256) Wg[i] = gw[i];
    if (tid < HH) gbs[tid] = gb[tid];
    bqs[tid] = biasQ[tid];
    __syncthreads();
    int nt0 = cg * 4;
    int hrow = tid & 15, hc0 = (tid >> 4) * 8;  // broadcast-friendly producer role
    auto produce = [&](int s, int buf) {
        const float4* zp = (const float4*)(z12 + ((size_t)s * NP + m0b + hrow) * FF);
        float4 z0 = zp[0], z1 = zp[1], z2 = zp[2], z3 = zp[3];
        float zr[16] = {z0.x, z0.y, z0.z, z0.w, z1.x, z1.y, z1.z, z1.w,
                        z2.x, z2.y, z2.z, z2.w, z3.x, z3.y, z3.z, z3.w};
        float sv[8];
#pragma unroll
        for (int c = 0; c < 8; c++) sv[c] = gbs[hc0 + c];
#pragma unroll
        for (int f = 0; f < 16; f++) {
            const float4* wp = (const float4*)(Wg + f * HH + hc0);
            float4 w0 = wp[0], w1 = wp[1];
            float zf = zr[f];
            sv[0] += zf * w0.x; sv[1] += zf * w0.y; sv[2] += zf * w0.z; sv[3] += zf * w0.w;
            sv[4] += zf * w1.x; sv[5] += zf * w1.y; sv[6] += zf * w1.z; sv[7] += zf * w1.w;
        }
        unsigned int res[4];
#pragma unroll
        for (int k = 0; k < 4; k++)
            res[k] = pck(fmaxf(sv[2 * k], 0.f), fmaxf(sv[2 * k + 1], 0.f));
        *(uint4*)&hgs[buf][hrow * 136 + hc0] = *(uint4*)res;
    };
    f32x4 acc[4];
#pragma unroll
    for (int j = 0; j < 4; j++) acc[j] = (f32x4){0.f, 0.f, 0.f, 0.f};
    produce(0, 0);
    __syncthreads();
    for (int s = 0; s < 12; s++) {
        int buf = s & 1;
        if (s < 11) produce(s + 1, buf ^ 1);    // overlaps with MFMA below
#pragma unroll
        for (int k2 = 0; k2 < 4; k2++) {
            int kb = s * 4 + k2;
            short8 bf[4];
#pragma unroll
            for (int j = 0; j < 4; j++)
                bf[j] = *(const short8*)(Bq + ((size_t)(kb * 16 + nt0 + j) * 64 + lane) * 8);
            short8 af = *(const short8*)&hgs[buf][mr * 136 + k2 * 32 + q * 8];
#pragma unroll
            for (int j = 0; j < 4; j++)
                acc[j] = __builtin_amdgcn_mfma_f32_16x16x32_bf16(af, bf[j], acc[j], 0, 0, 0);
        }
        __syncthreads();    // produce(s+1) done AND hgs[buf] reads done
    }
#pragma unroll
    for (int j = 0; j < 4; j++) {
        int c = (nt0 + j) * 16 + mr;
        float bv = bqs[c];
#pragma unroll
        for (int r = 0; r < 4; r++)
            csh[(q * 4 + r) * 264 + c] = f2b(acc[j][r] + bv);
    }
    __syncthreads();
#pragma unroll
    for (int i = 0; i < 2; i++) {
        int idx = i * 256 + tid;        // 0..511: 16 rows x 32 chunks
        int row = idx >> 5, c8 = (idx & 31) * 8;
        short8 v = *(const short8*)&csh[row * 264 + c8];
        if (c8 < 128) *(short8*)(out0 + (size_t)(m0b + row) * HH + c8) = v;
        else          *(short8*)(out1 + (size_t)(m0b + row) * HH + (c8 - 128)) = v;
    }
}

// hg A-fragment (decoder): lane computes 32 hg values for row mr of a 16-row block
__device__ __forceinline__ void hg_frag(const float* zsh, const float* Wg, const float* gbs,
                                        int mr, int q, short8* hgf) {
    float zr[16];
    {
        const float4* zp = (const float4*)(zsh + mr * FF);
        float4 z0 = zp[0], z1 = zp[1], z2 = zp[2], z3 = zp[3];
        zr[0] = z0.x; zr[1] = z0.y; zr[2] = z0.z; zr[3] = z0.w;
        zr[4] = z1.x; zr[5] = z1.y; zr[6] = z1.z; zr[7] = z1.w;
        zr[8] = z2.x; zr[9] = z2.y; zr[10] = z2.z; zr[11] = z2.w;
        zr[12] = z3.x; zr[13] = z3.y; zr[14] = z3.z; zr[15] = z3.w;
    }
#pragma unroll
    for (int k2 = 0; k2 < 4; k2++) {
        float s[8];
#pragma unroll
        for (int c = 0; c < 8; c++) s[c] = gbs[k2 * 32 + q * 8 + c];
#pragma unroll
        for (int f = 0; f < 16; f++) {
            const float4* wp = (const float4*)(Wg + f * HH + k2 * 32 + q * 8);
            float4 w0 = wp[0], w1 = wp[1];
            float zf = zr[f];
            s[0] += zf * w0.x; s[1] += zf * w0.y; s[2] += zf * w0.z; s[3] += zf * w0.w;
            s[4] += zf * w1.x; s[5] += zf * w1.y; s[6] += zf * w1.z; s[7] += zf * w1.w;
        }
#pragma unroll
        for (int c = 0; c < 8; c++) hgf[k2][c] = (short)f2b(fmaxf(s[c], 0.f));
    }
}

// ---------------- decoder fused step: [gather] + gemm + head + feedback ----------------
// 16-row blocks, 4 waves x (16 rows x 32 cols). (unchanged from R6/R7)
__global__ __launch_bounds__(256, 3) void k_gemmF2(const unsigned short* __restrict__ a0,
                                                   const unsigned short* __restrict__ a1,
                                                   const float* __restrict__ zt, int gather,
                                                   const float* __restrict__ gw,
                                                   const float* __restrict__ gb,
                                                   const unsigned short* __restrict__ Bpk,
                                                   const float* __restrict__ bias,
                                                   unsigned short* __restrict__ out,
                                                   const float* __restrict__ hw,
                                                   const float* __restrict__ hbv,
                                                   const float* __restrict__ dinvN,
                                                   const int* __restrict__ rp,
                                                   const unsigned short* __restrict__ csr,
                                                   unsigned short* __restrict__ xsD,
                                                   float* __restrict__ yout) {
    __shared__ float Wg[FF * HH];
    __shared__ float Whs[CC * 132];     // padded: kills 16-way head bank conflict
    __shared__ float gbs[HH], biasS[HH], hbS[CC];
    __shared__ float zsh[16 * FF];
    __shared__ __align__(16) unsigned short hgD[16 * 136];
    __shared__ unsigned short hsh[16 * 136];
    __shared__ float ysh[16 * 17];
    int tid = threadIdx.x;
    int wid = tid >> 6, lane = tid & 63;
    int m0b = blockIdx.x * 16;
    int mr = lane & 15, q = lane >> 4;
    for (int i = tid; i < FF * HH; i += 256) {
        Wg[i] = gw[i];
        Whs[(i >> 7) * 132 + (i & 127)] = hw[i];
    }
    if (tid < HH) { gbs[tid] = gb[tid]; biasS[tid] = bias[tid]; }
    if (tid < CC) hbS[tid] = hbv[tid];
    if (!gather) {
        if (tid < 16 * FF) zsh[tid] = zt[(size_t)m0b * FF + tid];
    } else {
        // in-tile 16-dim aggregation from xsD: 16 threads/row (2 halves x 8-way edges)
        int r = tid >> 4, p = tid & 15, half = p & 1, eo = p >> 1;
        int n = m0b + r;
        float a[8];
#pragma unroll
        for (int k = 0; k < 8; k++) a[k] = 0.f;
        if (n < NN) {
            int j0 = rp[n], j1 = rp[n + 1];
            for (int j = j0 + eo; j < j1; j += 8) {
                int s = csr[j];
                uint4 v = *(const uint4*)(xsD + (size_t)s * FF + half * 8);
                addrow(a, v);
            }
        }
#pragma unroll
        for (int k = 0; k < 8; k++) {
            a[k] += __shfl_xor(a[k], 2);
            a[k] += __shfl_xor(a[k], 4);
            a[k] += __shfl_xor(a[k], 8);
        }
        if (n < NN && eo == 0) {
            uint4 sv = *(const uint4*)(xsD + (size_t)n * FF + half * 8);
            addrow(a, sv);
            float dn = dinvN[n];
#pragma unroll
            for (int k = 0; k < 8; k++) zsh[r * FF + half * 8 + k] = a[k] * dn;
        }
    }
    __syncthreads();
    if (wid == 0) {
        short8 hgf[4];
        hg_frag(zsh, Wg, gbs, mr, q, hgf);
#pragma unroll
        for (int k2 = 0; k2 < 4; k2++)
            *(short8*)&hgD[mr * 136 + k2 * 32 + q * 8] = hgf[k2];
    }
    __syncthreads();
    int nt0 = wid * 2;                  // wave's 2 col tiles (32 cols)
    f32x4 acc[2];
#pragma unroll
    for (int j = 0; j < 2; j++) acc[j] = (f32x4){0.f, 0.f, 0.f, 0.f};
#pragma unroll
    for (int ki = 0; ki < 12; ki++) {
        short8 bf[2];
#pragma unroll
        for (int j = 0; j < 2; j++)
            bf[j] = *(const short8*)(Bpk + (size_t)((ki * 8 + nt0 + j) * 64 + lane) * 8);
        short8 af;
        if (ki < 4)
            af = *(const short8*)(a0 + (size_t)(m0b + mr) * HH + ki * 32 + q * 8);
        else if (ki < 8)
            af = *(const short8*)(a1 + (size_t)(m0b + mr) * HH + (ki - 4) * 32 + q * 8);
        else
            af = *(const short8*)&hgD[mr * 136 + (ki - 8) * 32 + q * 8];
#pragma unroll
        for (int j = 0; j < 2; j++)
            acc[j] = __builtin_amdgcn_mfma_f32_16x16x32_bf16(af, bf[j], acc[j], 0, 0, 0);
    }
#pragma unroll
    for (int j = 0; j < 2; j++) {
        int feat = (nt0 + j) * 16 + mr;
        float bv = biasS[feat];
#pragma unroll
        for (int r = 0; r < 4; r++)
            hsh[(q * 4 + r) * 136 + feat] = f2b(acc[j][r] + bv);
    }
    __syncthreads();
    // coalesced h write-out (16B/lane): 16 rows x 16 chunks = 256
    {
        int row = tid >> 4, c8 = (tid & 15) * 8;
        *(short8*)(out + (size_t)(m0b + row) * HH + c8) =
            *(const short8*)&hsh[row * 136 + c8];
    }
    // head: y[n][c] = hb[c] + sum_k h[n][k]*Wh[c][k]; 1 thread per (row, col)
    {
        int r = tid >> 4, c = tid & 15;
        float y = hbS[c];
        for (int k = 0; k < HH; k++)
            y += blo((unsigned int)hsh[r * 136 + k]) * Whs[c * 132 + k];
        ysh[r * 17 + c] = y;
        int gn = m0b + r;
        if (gn < NN) yout[(size_t)gn * CC + c] = y;
    }
    __syncthreads();
    // next-step xs: xsD[n][k] = bf16(y[n][k] * dinv[n])
    if (tid < 16) {
        int gn = m0b + tid;
        if (gn < NN) {
            float dn = dinvN[gn];
            unsigned int res[8];
#pragma unroll
            for (int k = 0; k < 8; k++)
                res[k] = pck(ysh[tid * 17 + 2 * k] * dn, ysh[tid * 17 + 2 * k + 1] * dn);
            uint4* dst = (uint4*)(xsD + (size_t)gn * FF);
            dst[0] = *(uint4*)(res);
            dst[1] = *(uint4*)(res + 4);
        }
    }
}

extern "C" void kernel_launch(void* const* d_in, const int* in_sizes, int n_in,
                              void* d_out, int out_size, void* d_ws, size_t ws_size,
                              hipStream_t stream) {
    const float* x_seq  = (const float*)d_in[0];
    const int*   ei     = (const int*)d_in[1];
    const float* gcn_w  = (const float*)d_in[5];
    const float* gcn_b  = (const float*)d_in[6];
    const float* conv_w = (const float*)d_in[7];
    const float* conv_b = (const float*)d_in[8];
    const float* proj_w = (const float*)d_in[9];
    const float* proj_b = (const float*)d_in[10];
    const float* head_w = (const float*)d_in[11];
    const float* head_b = (const float*)d_in[12];
    float* outp = (float*)d_out;

    char* ws = (char*)d_ws;
    size_t off = 0;
    auto alloc = [&](size_t bytes) { void* p = ws + off; off += (bytes + 255) & ~(size_t)255; return p; };
    // persistent
    float*          dinv   = (float*)alloc((size_t)TT * NN * 4);
    int*            rowptr = (int*)alloc((size_t)TT * (NN + 1) * 4);
    unsigned short* csr    = (unsigned short*)alloc((size_t)TT * EE * 2);
    unsigned short* hb0    = (unsigned short*)alloc((size_t)NP * HH * 2);
    unsigned short* hb1    = (unsigned short*)alloc((size_t)NP * HH * 2);
    unsigned short* hb2    = (unsigned short*)alloc((size_t)NP * HH * 2);
    unsigned short* hb3    = (unsigned short*)alloc((size_t)NP * HH * 2);
    unsigned short* xsD    = (unsigned short*)alloc((size_t)NP * FF * 2);
    unsigned short* Bpk    = (unsigned short*)alloc((size_t)384 * HH * 2);
    float*          Bf32   = (float*)alloc((size_t)384 * HH * 4);
    float*          biasT  = (float*)alloc(HH * 4);
    // transient B: encoder xs + z + Bq
    size_t tb = off;
    unsigned short* xs12  = (unsigned short*)alloc((size_t)TT * NN * FF * 2);
    float*          z12   = (float*)alloc((size_t)TT * NP * FF * 4);
    unsigned short* Bq    = (unsigned short*)alloc((size_t)48 * 16 * 64 * 8 * 2);
    float*          biasQ = (float*)alloc(256 * 4);
    size_t compute_end = off;
    // transient A: CSR-build scratch, aliased over transient B
    off = tb;
    int* gData = (int*)alloc((size_t)TT * WPT * CHE * 4);
    int* pcnt  = (int*)alloc((size_t)TT * WPT * NB * 4);
    int* pofs  = (int*)alloc((size_t)TT * WPT * NB * 4);
    int* bbase = (int*)alloc((size_t)TT * NB * 4);
    size_t csr_end = off;
    bool fastcsr = (csr_end <= ws_size && compute_end <= ws_size);

    if (fastcsr) {
        k_binA<<<TT * WPT, 512, 0, stream>>>(ei, gData, pcnt, pofs);
        k_bscan2<<<TT, 512, 0, stream>>>(pcnt, bbase, rowptr);
        k_placeB<<<TT * NB, 256, 0, stream>>>(gData, pcnt, pofs, bbase, rowptr, dinv, csr);
    } else {
        off = tb;
        int* cnt  = (int*)alloc((size_t)TT * NN * 4);
        int* wofs = (int*)alloc((size_t)TT * NN * 4);
        k_zero<<<(TT * NN + 255) / 256, 256, 0, stream>>>(cnt, TT * NN);
        k_count<<<(TT * EE + 255) / 256, 256, 0, stream>>>(ei, cnt);
        k_dinvF<<<(TT * NN + 255) / 256, 256, 0, stream>>>(cnt, dinv);
        k_scan<<<TT, 1024, 0, stream>>>(cnt, rowptr, wofs);
        k_place<<<(TT * EE + 255) / 256, 256, 0, stream>>>(ei, wofs, csr);
    }

    k_wprepB<<<193, 256, 0, stream>>>(conv_w, proj_w, conv_b, proj_b, Bpk, Bf32, biasT);
    k_tchain<<<129, 128, 0, stream>>>(Bf32, biasT, Bq, biasQ);

    // encoder front-end: xs, aggregation, then ONE fused hg+composed gemm
    k_xs<<<(TT * NN + 255) / 256, 256, 0, stream>>>(x_seq, dinv, xs12);
    k_aggX<<<AGG_GRID, 256, 0, stream>>>(xs12, csr, rowptr, dinv, z12);
    k_gemmE<<<NP / 16, 256, 0, stream>>>(z12, gcn_w, gcn_b, Bq, biasQ, hb2, hb3);   // h10 -> hb2, h11 -> hb3

    // decoder: t=12 reuses z(t=11); later steps gather in-tile from xsD
    unsigned short* hbuf[4] = {hb0, hb1, hb2, hb3};
    const float* dinv11 = dinv + (size_t)(TT - 1) * NN;
    const int* rp11 = rowptr + (size_t)(TT - 1) * (NN + 1);
    const unsigned short* csr11 = csr + (size_t)(TT - 1) * EE;
    for (int t = TT; t < TT + HOR; t++) {
        const float* zt = (t == TT) ? (z12 + (size_t)(TT - 1) * NP * FF) : nullptr;
        k_gemmF2<<<NP / 16, 256, 0, stream>>>(hbuf[(t + 2) & 3], hbuf[(t + 3) & 3],
                                              zt, (t == TT) ? 0 : 1,
                                              gcn_w, gcn_b, Bpk, biasT, hbuf[t & 3],
                                              head_w, head_b, dinv11, rp11, csr11,
                                              xsD, outp + (size_t)(t - TT) * NN * CC);
    }
}